// Round 16
// baseline (2529.626 us; speedup 1.0000x reference)
//
#include <hip/hip_runtime.h>
#include <hip/hip_bf16.h>
#include <math.h>

// ---------------------------------------------------------------------------
// HMABottleneck: B=4, C=512, H=W=16, DI=1024, K=4 dirs, N=16 states, R=32
// Round 16: multi-step-per-lane wave scan (SPL=4 for L=256: local affine
// compose, ONE 6-step shfl scan, exclusive prefix, local re-walk).
// Rest = round 13 baseline (2.44ms). ASCII-only, single code block.
// ---------------------------------------------------------------------------

constexpr int B_  = 4;
constexpr int C_  = 512;
constexpr int DI_ = 1024;
constexpr int K_  = 4;
constexpr int N_  = 16;
constexpr int R_  = 32;
constexpr float BNS_ = 0.9999950000374997f;   // 1/sqrt(1+1e-5)

__device__ inline float geluf(float x) {
    return 0.5f * x * (1.0f + erff(x * 0.70710678118654752f));
}
__device__ inline float siluf(float x) {
    return x / (1.0f + expf(-x));
}
__device__ inline float softplusf(float x) {
    return fmaxf(x, 0.0f) + log1pf(expf(-fabsf(x)));
}

__device__ inline float blockReduceSum(float v, float* sd) {
    int tid = threadIdx.x;
    sd[tid] = v; __syncthreads();
    for (int s = blockDim.x / 2; s > 0; s >>= 1) {
        if (tid < s) sd[tid] += sd[tid + s];
        __syncthreads();
    }
    float r = sd[0]; __syncthreads();
    return r;
}

// --------------------------- LN over channels (NCHW -> (B*L, C)) -----------
__global__ void k_ln_nchw(const float* __restrict__ x, const float* __restrict__ w,
                          const float* __restrict__ b, float* __restrict__ out,
                          int L, float eps) {
    int row = blockIdx.x;            // b*L + l
    int bb = row / L, l = row % L;
    __shared__ float sd[256];
    __shared__ float srow[C_];
    const float* xp = x + (size_t)bb * C_ * L + l;
    float sum = 0.f;
    for (int c = threadIdx.x; c < C_; c += 256) { float v = xp[(size_t)c * L]; srow[c] = v; sum += v; }
    sum = blockReduceSum(sum, sd);
    float mu = sum / C_;
    float vs = 0.f;
    for (int c = threadIdx.x; c < C_; c += 256) { float d = srow[c] - mu; vs += d * d; }
    vs = blockReduceSum(vs, sd);
    float rstd = rsqrtf(vs / C_ + eps);
    float* op = out + (size_t)row * C_;
    for (int c = threadIdx.x; c < C_; c += 256) op[c] = (srow[c] - mu) * rstd * w[c] + b[c];
}

// --------------------------- tiled f32 GEMM: out = A (M,K) * Bw(N,K)^T -----
template <int EPI>
__global__ void k_gemm_nt(const float* __restrict__ A, const float* __restrict__ Bw,
                          float* __restrict__ Cout, int M, int Nn, int Kk,
                          const float* __restrict__ Res, int L) {
    const int BK = 16;
    __shared__ float As[BK][65];
    __shared__ float Bs[BK][65];
    int m0 = blockIdx.y * 64, n0 = blockIdx.x * 64;
    int tid = threadIdx.x;
    int tx = tid % 16, ty = tid / 16;
    float acc[4][4] = {};
    for (int k0 = 0; k0 < Kk; k0 += BK) {
        int mm = tid >> 2;
        int kk = (tid & 3) * 4;
        float4 va = *reinterpret_cast<const float4*>(A + (size_t)(m0 + mm) * Kk + k0 + kk);
        As[kk + 0][mm] = va.x; As[kk + 1][mm] = va.y; As[kk + 2][mm] = va.z; As[kk + 3][mm] = va.w;
        float4 vb = *reinterpret_cast<const float4*>(Bw + (size_t)(n0 + mm) * Kk + k0 + kk);
        Bs[kk + 0][mm] = vb.x; Bs[kk + 1][mm] = vb.y; Bs[kk + 2][mm] = vb.z; Bs[kk + 3][mm] = vb.w;
        __syncthreads();
#pragma unroll
        for (int k = 0; k < BK; ++k) {
            float a[4], b2[4];
#pragma unroll
            for (int i = 0; i < 4; i++) a[i] = As[k][ty + 16 * i];
#pragma unroll
            for (int j = 0; j < 4; j++) b2[j] = Bs[k][tx + 16 * j];
#pragma unroll
            for (int i = 0; i < 4; i++)
#pragma unroll
                for (int j = 0; j < 4; j++) acc[i][j] += a[i] * b2[j];
        }
        __syncthreads();
    }
#pragma unroll
    for (int i = 0; i < 4; i++) {
        int m = m0 + ty + 16 * i;
#pragma unroll
        for (int j = 0; j < 4; j++) {
            int n = n0 + tx + 16 * j;
            if (EPI == 0) {
                Cout[(size_t)m * Nn + n] = acc[i][j];
            } else {
                int bb = m / L, l = m % L;
                size_t o = ((size_t)bb * C_ + n) * L + l;
                Cout[o] = Res[o] + acc[i][j];
            }
        }
    }
}

// --------------------------- depthwise 3x3 (pad1) + bias + SiLU ------------
// writes xm (b,l,d) AND transposed xmT (b,d,l) for the wave-scan u-gather
__global__ void k_dwconv_silu(const float* __restrict__ xz, const float* __restrict__ cw,
                              const float* __restrict__ cb, float* __restrict__ xm,
                              float* __restrict__ xmT, int H, int W) {
    int L = H * W;
    int idx = blockIdx.x * 256 + threadIdx.x;            // (b, l, d) d fastest
    int total = B_ * L * DI_;
    if (idx >= total) return;
    int d = idx % DI_; int t = idx / DI_; int l = t % L; int bb = t / L;
    int h = l / W, w = l % W;
    float acc = cb[d];
    const float* wp = cw + d * 9;
#pragma unroll
    for (int dy = 0; dy < 3; dy++) {
        int hh = h + dy - 1;
        if ((unsigned)hh >= (unsigned)H) continue;
#pragma unroll
        for (int dx = 0; dx < 3; dx++) {
            int ww = w + dx - 1;
            if ((unsigned)ww >= (unsigned)W) continue;
            acc += xz[((size_t)bb * L + hh * W + ww) * (2 * DI_) + d] * wp[dy * 3 + dx];
        }
    }
    float v = siluf(acc);
    xm[idx] = v;
    xmT[((size_t)bb * DI_ + d) * L + l] = v;
}

// map (k,l) -> source flat index in row-major (h*W+w) order
__device__ inline int dir_src(int k, int l, int H, int W, int L) {
    int ll = (k >= 2) ? (L - 1 - l) : l;
    return (k & 1) ? ((ll % H) * W + ll / H) : ll;
}

// --------------------------- x_dbl (LDS row staging, 64 thr/block) ---------
__global__ void k_xdbl(const float* __restrict__ xm, const float* __restrict__ xproj,
                       float* __restrict__ xdbl, int H, int W) {
    int L = H * W;
    int blk = blockIdx.x;            // (b,k,l)
    int l = blk % L; int t = blk / L; int k = t % K_; int bb = t / K_;
    int src = dir_src(k, l, H, W, L);
    __shared__ float row[DI_];
    const float* xp = xm + ((size_t)bb * L + src) * DI_;
    for (int d = threadIdx.x; d < DI_; d += 64) row[d] = xp[d];
    __syncthreads();
    const float* wp = xproj + ((size_t)k * 64 + threadIdx.x) * DI_;
    float acc = 0.f;
    for (int d = 0; d < DI_; d++) acc += row[d] * wp[d];
    xdbl[((size_t)(bb * K_ + k) * 64 + threadIdx.x) * L + l] = acc;
}

// --------------------------- wave scan, SPL steps per lane -----------------
// One 64-lane wave per (b,k,d); lane j owns steps [j*SPL, (j+1)*SPL).
// Local serial compose of SPL affine maps T=(a,b) (h -> a*h + b), then ONE
// Hillis-Steele shfl_up inclusive scan over CW lanes covers all L steps.
// h starts at 0 so inclusive h at lane j = scanned b; exclusive prefix
// h_in = shfl_up(scanned b, 1) (0 at lane 0); then re-walk SPL local steps.
// block = 256 threads = 4 waves (4 consecutive d); grid = B*K*(DI/4).
template <int LT>
__global__ void k_scan_wave(const float* __restrict__ xmT, const float* __restrict__ xdbl,
                            const float* __restrict__ dtw, const float* __restrict__ dtb,
                            const float* __restrict__ Alog, const float* __restrict__ Dp,
                            float* __restrict__ part, int H, int W) {
    constexpr int SPL = (LT == 256) ? 4 : 1;
    constexpr int CW  = (LT < 64) ? LT : 64;
    const int L = LT;
    int lane = threadIdx.x & 63;
    int wv = threadIdx.x >> 6;
    int blk = blockIdx.x;                // (bb, k, dq)
    const int ndq = DI_ / 4;
    int dq = blk % ndq; int t2 = blk / ndq; int k = t2 % K_; int bb = t2 / K_;
    int d = dq * 4 + wv;

    const float* wrow = dtw + ((size_t)k * DI_ + d) * R_;     // wave-uniform
    const float* al   = Alog + ((size_t)k * DI_ + d) * N_;
    float bias = dtb[k * DI_ + d];
    float Dv   = Dp[k * DI_ + d];
    float A[N_];
#pragma unroll
    for (int n = 0; n < N_; n++) A[n] = -expf(al[n]);

    const float* bc = xdbl + (size_t)(bb * K_ + k) * 64 * L;
    const float* ut = xmT + ((size_t)bb * DI_ + d) * L;
    float* yb = part + (size_t)(bb * K_ + k) * L * DI_ + d;

    int lj = lane < CW ? lane : CW - 1;      // lanes >= CW duplicate last step
    int base = lj * SPL;

    // delta + u for the SPL owned steps
    float dl[SPL], du[SPL], uu[SPL], y[SPL];
    {
        float accv[SPL];
#pragma unroll
        for (int i = 0; i < SPL; i++) accv[i] = bias;
#pragma unroll
        for (int r = 0; r < R_; r++) {
            float wr = wrow[r];
            if constexpr (SPL == 4) {
                float4 d4 = *reinterpret_cast<const float4*>(bc + (size_t)r * L + base);
                accv[0] += d4.x * wr; accv[1] += d4.y * wr;
                accv[2] += d4.z * wr; accv[3] += d4.w * wr;
            } else {
                accv[0] += bc[(size_t)r * L + base] * wr;
            }
        }
#pragma unroll
        for (int i = 0; i < SPL; i++) {
            int src = dir_src(k, base + i, H, W, L);
            dl[i] = softplusf(accv[i]);
            uu[i] = ut[src];
            du[i] = dl[i] * uu[i];
            y[i] = 0.f;
        }
    }

#pragma unroll
    for (int n = 0; n < N_; n++) {
        float a[SPL], b[SPL], Cv[SPL];
        if constexpr (SPL == 4) {
            float4 B4 = *reinterpret_cast<const float4*>(bc + (size_t)(R_ + n) * L + base);
            float4 C4 = *reinterpret_cast<const float4*>(bc + (size_t)(R_ + N_ + n) * L + base);
            b[0] = du[0] * B4.x; b[1] = du[1] * B4.y; b[2] = du[2] * B4.z; b[3] = du[3] * B4.w;
            Cv[0] = C4.x; Cv[1] = C4.y; Cv[2] = C4.z; Cv[3] = C4.w;
        } else {
            b[0] = du[0] * bc[(size_t)(R_ + n) * L + base];
            Cv[0] = bc[(size_t)(R_ + N_ + n) * L + base];
        }
#pragma unroll
        for (int i = 0; i < SPL; i++) a[i] = expf(dl[i] * A[n]);
        // local compose: T_total = T_{SPL-1} o ... o T_0
        float aL = a[0], bL = b[0];
#pragma unroll
        for (int i = 1; i < SPL; i++) { bL = a[i] * bL + b[i]; aL = a[i] * aL; }
        // wave inclusive scan over CW lanes
#pragma unroll
        for (int off = 1; off < CW; off <<= 1) {
            float ap = __shfl_up(aL, off);
            float bp = __shfl_up(bL, off);
            if (lane >= off) { bL = aL * bp + bL; aL = aL * ap; }
        }
        // exclusive prefix h_in
        float hin = __shfl_up(bL, 1);
        if (lane == 0) hin = 0.f;
        float h = hin;
#pragma unroll
        for (int i = 0; i < SPL; i++) { h = a[i] * h + b[i]; y[i] += h * Cv[i]; }
    }

    if (lane < CW) {
#pragma unroll
        for (int i = 0; i < SPL; i++) {
            int src = dir_src(k, base + i, H, W, L);
            yb[(size_t)src * DI_] = y[i] + Dv * uu[i];
        }
    }
}

// --------------------------- merge 4 direction partials --------------------
__global__ void k_merge4(const float* __restrict__ part, float* __restrict__ ybuf,
                         int L) {
    int idx = blockIdx.x * 256 + threadIdx.x;    // (b,l,d)
    int total = B_ * L * DI_;
    if (idx >= total) return;
    int d = idx % DI_; int t = idx / DI_; int l = t % L; int bb = t / L;
    size_t s = ((size_t)bb * K_ * L + l) * DI_ + d;
    float v = part[s] + part[s + (size_t)L * DI_] + part[s + (size_t)2 * L * DI_]
            + part[s + (size_t)3 * L * DI_];
    ybuf[idx] = v;
}

// --------------------------- LN(y) * silu(z) -> t (B*L, DI) ----------------
__global__ void k_ln_silu(const float* __restrict__ y, const float* __restrict__ xz,
                          const float* __restrict__ onw, const float* __restrict__ onb,
                          float* __restrict__ tout) {
    int row = blockIdx.x;            // b*L + l
    __shared__ float sd[256];
    __shared__ float srow[DI_];
    const float* yp = y + (size_t)row * DI_;
    float sum = 0.f;
    for (int d = threadIdx.x; d < DI_; d += 256) { float v = yp[d]; srow[d] = v; sum += v; }
    sum = blockReduceSum(sum, sd);
    float mu = sum / DI_;
    float vs = 0.f;
    for (int d = threadIdx.x; d < DI_; d += 256) { float dv = srow[d] - mu; vs += dv * dv; }
    vs = blockReduceSum(vs, sd);
    float rstd = rsqrtf(vs / DI_ + 1e-5f);
    const float* zp = xz + (size_t)row * 2 * DI_ + DI_;
    float* tp = tout + (size_t)row * DI_;
    for (int d = threadIdx.x; d < DI_; d += 256) {
        float zn = zp[d];
        tp[d] = ((srow[d] - mu) * rstd * onw[d] + onb[d]) * siluf(zn);
    }
}

// --------------------------- downsample: dw conv s2 + BN + GELU ------------
__global__ void k_dwconv_s2_bn_gelu(const float* __restrict__ x, const float* __restrict__ dw,
                                    const float* __restrict__ bns, const float* __restrict__ bnb,
                                    float* __restrict__ out, int Hi, int Wi) {
    int Ho = Hi / 2, Wo = Wi / 2;
    int idx = blockIdx.x * 256 + threadIdx.x;            // (b,c,ho,wo)
    int total = B_ * C_ * Ho * Wo;
    if (idx >= total) return;
    int wo = idx % Wo; int t = idx / Wo; int ho = t % Ho; t /= Ho; int c = t % C_; int bb = t / C_;
    float acc = 0.f;
    const float* xp = x + ((size_t)bb * C_ + c) * Hi * Wi;
    const float* wp = dw + c * 9;
#pragma unroll
    for (int dy = 0; dy < 3; dy++) {
        int ih = ho * 2 + dy - 1;
        if ((unsigned)ih >= (unsigned)Hi) continue;
#pragma unroll
        for (int dx = 0; dx < 3; dx++) {
            int iw = wo * 2 + dx - 1;
            if ((unsigned)iw >= (unsigned)Wi) continue;
            acc += xp[ih * Wi + iw] * wp[dy * 3 + dx];
        }
    }
    acc = acc * (bns[c] * BNS_) + bnb[c];
    out[idx] = geluf(acc);
}

// --------------------------- pointwise 1x1 conv + BN + GELU ----------------
__global__ void k_pwconv_bn_gelu(const float* __restrict__ x, const float* __restrict__ pw,
                                 const float* __restrict__ bns, const float* __restrict__ bnb,
                                 float* __restrict__ out, int L) {
    int idx = blockIdx.x * 256 + threadIdx.x;            // (b,co,l)
    int total = B_ * C_ * L;
    if (idx >= total) return;
    int l = idx % L; int t = idx / L; int co = t % C_; int bb = t / C_;
    const float* xp = x + (size_t)bb * C_ * L + l;
    const float* wp = pw + (size_t)co * C_;
    float acc = 0.f;
    for (int ci = 0; ci < C_; ci++) acc += xp[(size_t)ci * L] * wp[ci];
    acc = acc * (bns[co] * BNS_) + bnb[co];
    out[idx] = geluf(acc);
}

// --------------------------- 3x3 conv, split-C partial (r11 body) ----------
__global__ void k_conv3x3_part(const float* __restrict__ x, const float* __restrict__ wgt,
                               float* __restrict__ partial, int H, int W) {
    const int COB = 4, CH = 4, SPLIT = 4;
    const int CSEG = C_ / SPLIT;         // 128
    int L = H * W;                       // == blockDim.x
    int t = threadIdx.x;
    int h = t / W, w = t % W;
    int blk = blockIdx.x;
    int s = blk % SPLIT; int t2 = blk / SPLIT;
    int ng = C_ / COB;
    int cg = t2 % ng; int bb = t2 / ng;
    int co0 = cg * COB;
    __shared__ float sp[2][CH * 256];
    float acc[COB];
#pragma unroll
    for (int j = 0; j < COB; j++) acc[j] = 0.f;
    const float* xb = x + (size_t)bb * C_ * L;
    int cbeg = s * CSEG;
    float4 pre = *reinterpret_cast<const float4*>(xb + (size_t)cbeg * L + 4 * t);
    int p = 0;
    for (int c0 = cbeg; c0 < cbeg + CSEG; c0 += CH) {
        *reinterpret_cast<float4*>(&sp[p][4 * t]) = pre;
        __syncthreads();
        if (c0 + CH < cbeg + CSEG)
            pre = *reinterpret_cast<const float4*>(xb + (size_t)(c0 + CH) * L + 4 * t);
#pragma unroll 1
        for (int ci = 0; ci < CH; ci++) {
            const float* pl = &sp[p][ci * L];
            float v[9];
#pragma unroll
            for (int dy = 0; dy < 3; dy++) {
                int hh = h + dy - 1;
                bool hok = (unsigned)hh < (unsigned)H;
#pragma unroll
                for (int dx = 0; dx < 3; dx++) {
                    int ww = w + dx - 1;
                    bool ok = hok && ((unsigned)ww < (unsigned)W);
                    v[dy * 3 + dx] = ok ? pl[hh * W + ww] : 0.f;
                }
            }
            const float* wr = wgt + ((size_t)co0 * C_ + c0 + ci) * 9;
#pragma unroll
            for (int j = 0; j < COB; j++) {
                const float* wj = wr + (size_t)j * C_ * 9;
                float a = acc[j];
                a += v[0] * wj[0] + v[1] * wj[1] + v[2] * wj[2];
                a += v[3] * wj[3] + v[4] * wj[4] + v[5] * wj[5];
                a += v[6] * wj[6] + v[7] * wj[7] + v[8] * wj[8];
                acc[j] = a;
            }
        }
        p ^= 1;
    }
    size_t base = (size_t)s * B_ * C_ * L;
#pragma unroll
    for (int j = 0; j < COB; j++)
        partial[base + ((size_t)bb * C_ + co0 + j) * L + t] = acc[j];
}

// --------------------------- conv finish: sum 4 partials + epilogue --------
template <int MODE>
__global__ void k_conv_fin(const float* __restrict__ part4, const float* __restrict__ bns,
                           const float* __restrict__ bnb, const float* __restrict__ res,
                           float* __restrict__ out, int L) {
    int idx = blockIdx.x * 256 + threadIdx.x;    // (b,c,l)
    int total = B_ * C_ * L;
    if (idx >= total) return;
    int c = (idx / L) % C_;
    size_t T = (size_t)total;
    float a = part4[idx] + part4[idx + T] + part4[idx + 2 * T] + part4[idx + 3 * T];
    a = a * (bns[c] * BNS_) + bnb[c];
    if (MODE == 0) out[idx] = geluf(a);
    else if (MODE == 1) out[idx] = geluf(a + res[idx]);
    else out[idx] = geluf(a) + res[idx];
}

// --------------------------- bilinear up + skip add ------------------------
__global__ void k_up_add(const float* __restrict__ low, const float* __restrict__ skip,
                         float* __restrict__ out, int Hi, int Wi, int Ho, int Wo) {
    int idx = blockIdx.x * 256 + threadIdx.x;            // (b,c,ho,wo)
    int total = B_ * C_ * Ho * Wo;
    if (idx >= total) return;
    int wo = idx % Wo; int t = idx / Wo; int ho = t % Ho; t /= Ho; int c = t % C_; int bb = t / C_;
    float fy = (float)ho * (float)(Hi - 1) / (float)(Ho - 1);
    float fx = (float)wo * (float)(Wi - 1) / (float)(Wo - 1);
    int y0 = (int)floorf(fy); int y1 = min(y0 + 1, Hi - 1); float wy = fy - (float)y0;
    int x0 = (int)floorf(fx); int x1 = min(x0 + 1, Wi - 1); float wx = fx - (float)x0;
    const float* lp = low + ((size_t)bb * C_ + c) * Hi * Wi;
    float g0 = lp[y0 * Wi + x0] * (1.f - wy) + lp[y1 * Wi + x0] * wy;
    float g1 = lp[y0 * Wi + x1] * (1.f - wy) + lp[y1 * Wi + x1] * wy;
    out[idx] = skip[idx] + g0 * (1.f - wx) + g1 * wx;
}

// --------------------------- BN + GELU elementwise -------------------------
__global__ void k_bn_gelu(const float* __restrict__ x, const float* __restrict__ s,
                          const float* __restrict__ b, float* __restrict__ out, int L) {
    int idx = blockIdx.x * 256 + threadIdx.x;            // (b,c,l)
    int total = B_ * C_ * L;
    if (idx >= total) return;
    int t = idx / L; int c = t % C_;
    out[idx] = geluf(x[idx] * (s[c] * BNS_) + b[c]);
}

// --------------------------- diagnostic fill (f32) -------------------------
__global__ void k_fill_out(float* o, int n, float v) {
    int i = blockIdx.x * 256 + threadIdx.x;
    if (i < n) o[i] = v;
}

// ===========================================================================
struct VssW {
    const float *lnw, *lnb, *inproj, *convw, *convb, *xproj, *dtw, *dtb, *Alog, *D, *onw, *onb, *outproj;
};

static void run_vss(const float* xc_in, float* xc_out, const VssW& p, int H, int W,
                    float* xln, float* xz, float* xm, float* xmT, float* xdbl,
                    float* part, float* ybuf, float* tbuf, hipStream_t stream) {
    int L = H * W, M = B_ * L;
    k_ln_nchw<<<M, 256, 0, stream>>>(xc_in, p.lnw, p.lnb, xln, L, 1e-6f);
    {
        dim3 g(2 * DI_ / 64, M / 64);
        k_gemm_nt<0><<<g, 256, 0, stream>>>(xln, p.inproj, xz, M, 2 * DI_, C_, nullptr, L);
    }
    {
        int tot = B_ * L * DI_;
        k_dwconv_silu<<<(tot + 255) / 256, 256, 0, stream>>>(xz, p.convw, p.convb, xm, xmT, H, W);
    }
    k_xdbl<<<B_ * K_ * L, 64, 0, stream>>>(xm, p.xproj, xdbl, H, W);
    {
        int g = B_ * K_ * (DI_ / 4);
        if (L == 256)
            k_scan_wave<256><<<g, 256, 0, stream>>>(xmT, xdbl, p.dtw, p.dtb, p.Alog, p.D, part, H, W);
        else if (L == 64)
            k_scan_wave<64><<<g, 256, 0, stream>>>(xmT, xdbl, p.dtw, p.dtb, p.Alog, p.D, part, H, W);
        else
            k_scan_wave<16><<<g, 256, 0, stream>>>(xmT, xdbl, p.dtw, p.dtb, p.Alog, p.D, part, H, W);
    }
    {
        int tot = B_ * L * DI_;
        k_merge4<<<(tot + 255) / 256, 256, 0, stream>>>(part, ybuf, L);
    }
    k_ln_silu<<<M, 256, 0, stream>>>(ybuf, xz, p.onw, p.onb, tbuf);
    {
        dim3 g(C_ / 64, M / 64);
        k_gemm_nt<1><<<g, 256, 0, stream>>>(tbuf, p.outproj, xc_out, M, C_, DI_, xc_in, L);
    }
}

extern "C" void kernel_launch(void* const* d_in, const int* in_sizes, int n_in,
                              void* d_out, int out_size, void* d_ws, size_t ws_size,
                              hipStream_t stream) {
    constexpr size_t NEED_FLOATS = 12124160;
    constexpr size_t NEED_BYTES  = NEED_FLOATS * 4;   // 48,496,640
    if (ws_size < NEED_BYTES) {
        k_fill_out<<<(out_size + 255) / 256, 256, 0, stream>>>((float*)d_out, out_size, 0.0f);
        return;
    }

    const float* x        = (const float*)d_in[0];
    const float* lnw      = (const float*)d_in[1];
    const float* lnb      = (const float*)d_in[2];
    const float* inproj   = (const float*)d_in[3];
    const float* convw    = (const float*)d_in[4];
    const float* convb    = (const float*)d_in[5];
    const float* xprojp   = (const float*)d_in[6];
    const float* dtwp     = (const float*)d_in[7];
    const float* dtbp     = (const float*)d_in[8];
    const float* Alogp    = (const float*)d_in[9];
    const float* Dpp      = (const float*)d_in[10];
    const float* onwp     = (const float*)d_in[11];
    const float* onbp     = (const float*)d_in[12];
    const float* outprojp = (const float*)d_in[13];
    const float* ds_dw    = (const float*)d_in[14];
    const float* ds_bn1s  = (const float*)d_in[15];
    const float* ds_bn1b  = (const float*)d_in[16];
    const float* ds_pw    = (const float*)d_in[17];
    const float* ds_bn2s  = (const float*)d_in[18];
    const float* ds_bn2b  = (const float*)d_in[19];
    const float* fus_c1   = (const float*)d_in[20];
    const float* fus_bn1s = (const float*)d_in[21];
    const float* fus_bn1b = (const float*)d_in[22];
    const float* fus_c2   = (const float*)d_in[23];
    const float* fus_bn2s = (const float*)d_in[24];
    const float* fus_bn2b = (const float*)d_in[25];
    const float* op_bn0s  = (const float*)d_in[26];
    const float* op_bn0b  = (const float*)d_in[27];
    const float* op_conv  = (const float*)d_in[28];
    const float* op_bn1s  = (const float*)d_in[29];
    const float* op_bn1b  = (const float*)d_in[30];

    float* ws = (float*)d_ws;
    float* xln   = ws;                    // 524288
    float* xz    = ws + 524288;           // 2097152
    float* xm    = ws + 2621440;          // 1048576
    float* xdbl  = ws + 3670016;          // 262144
    float* ybuf  = ws + 3932160;          // 1048576
    float* part  = ws + 4980736;          // 4194304
    float* tbuf  = part;                  // alias: part dead before ln_silu
    float* t_a   = ws + 9175040;          // 524288
    float* xr    = ws + 9699328;          // 524288
    float* p1    = ws + 10223616;         // 131072
    float* p2    = ws + 10354688;         // 32768
    float* proc0 = ws + 10387456;         // 524288
    float* proc1 = ws + 10911744;         // 131072
    float* proc2 = ws + 11042816;         // 32768
    float* xmT   = ws + 11075584;         // 1048576 (transposed xm)
    float* p1pre = xz;                    // 131072
    float* p2pre = xz + 131072;           // 32768
    float* up1t  = xln;                   // 131072
    float* rbh1  = xln + 131072;          // 131072
    float* fus1  = xln + 262144;          // 131072
    float* up0t  = xm;                    // 524288
    float* rbh0  = part;                  // 524288
    float* fus0  = part + 524288;         // 524288
    float* hbuf  = part + 1048576;        // 524288
    float* cpart = part + 1572864;        // 2097152 (4 conv partials)

    VssW vp[5];
    for (int i = 0; i < 5; i++) {
        vp[i].lnw     = lnw + (size_t)i * C_;
        vp[i].lnb     = lnb + (size_t)i * C_;
        vp[i].inproj  = inproj + (size_t)i * 2 * DI_ * C_;
        vp[i].convw   = convw + (size_t)i * DI_ * 9;
        vp[i].convb   = convb + (size_t)i * DI_;
        vp[i].xproj   = xprojp + (size_t)i * K_ * 64 * DI_;
        vp[i].dtw     = dtwp + (size_t)i * K_ * DI_ * R_;
        vp[i].dtb     = dtbp + (size_t)i * K_ * DI_;
        vp[i].Alog    = Alogp + (size_t)i * K_ * DI_ * N_;
        vp[i].D       = Dpp + (size_t)i * K_ * DI_;
        vp[i].onw     = onwp + (size_t)i * DI_;
        vp[i].onb     = onbp + (size_t)i * DI_;
        vp[i].outproj = outprojp + (size_t)i * C_ * DI_;
    }

    // ---- stem: two VSS at 16x16 ----
    run_vss(x,   t_a, vp[0], 16, 16, xln, xz, xm, xmT, xdbl, part, ybuf, tbuf, stream);
    run_vss(t_a, xr,  vp[1], 16, 16, xln, xz, xm, xmT, xdbl, part, ybuf, tbuf, stream);

    // ---- down 0: 16 -> 8 ----
    k_dwconv_s2_bn_gelu<<<(B_ * C_ * 64 + 255) / 256, 256, 0, stream>>>(
        xr, ds_dw, ds_bn1s, ds_bn1b, p1pre, 16, 16);
    k_pwconv_bn_gelu<<<(B_ * C_ * 64 + 255) / 256, 256, 0, stream>>>(
        p1pre, ds_pw, ds_bn2s, ds_bn2b, p1, 64);
    // ---- down 1: 8 -> 4 ----
    k_dwconv_s2_bn_gelu<<<(B_ * C_ * 16 + 255) / 256, 256, 0, stream>>>(
        p1, ds_dw + (size_t)C_ * 9, ds_bn1s + C_, ds_bn1b + C_, p2pre, 8, 8);
    k_pwconv_bn_gelu<<<(B_ * C_ * 16 + 255) / 256, 256, 0, stream>>>(
        p2pre, ds_pw + (size_t)C_ * C_, ds_bn2s + C_, ds_bn2b + C_, p2, 16);

    // ---- per-scale VSS ----
    run_vss(xr, proc0, vp[2], 16, 16, xln, xz, xm, xmT, xdbl, part, ybuf, tbuf, stream);
    run_vss(p1, proc1, vp[3],  8,  8, xln, xz, xm, xmT, xdbl, part, ybuf, tbuf, stream);
    run_vss(p2, proc2, vp[4],  4,  4, xln, xz, xm, xmT, xdbl, part, ybuf, tbuf, stream);

    // ---- fuse i=1: up(proc2: 4->8) + proc1, resblk j=0 ----
    k_up_add<<<(B_ * C_ * 64 + 255) / 256, 256, 0, stream>>>(proc2, proc1, up1t, 4, 4, 8, 8);
    {
        dim3 gp(B_ * (C_ / 4) * 4);
        int tot = B_ * C_ * 64;
        k_conv3x3_part<<<gp, 64, 0, stream>>>(up1t, fus_c1, cpart, 8, 8);
        k_conv_fin<0><<<(tot + 255) / 256, 256, 0, stream>>>(cpart, fus_bn1s, fus_bn1b,
                                                             nullptr, rbh1, 64);
        k_conv3x3_part<<<gp, 64, 0, stream>>>(rbh1, fus_c2, cpart, 8, 8);
        k_conv_fin<1><<<(tot + 255) / 256, 256, 0, stream>>>(cpart, fus_bn2s, fus_bn2b,
                                                             up1t, fus1, 64);
    }
    // ---- fuse i=0: up(fus1: 8->16) + proc0, resblk j=1 ----
    k_up_add<<<(B_ * C_ * 256 + 255) / 256, 256, 0, stream>>>(fus1, proc0, up0t, 8, 8, 16, 16);
    {
        dim3 gp(B_ * (C_ / 4) * 4);
        int tot = B_ * C_ * 256;
        k_conv3x3_part<<<gp, 256, 0, stream>>>(up0t, fus_c1 + (size_t)C_ * C_ * 9, cpart, 16, 16);
        k_conv_fin<0><<<(tot + 255) / 256, 256, 0, stream>>>(cpart, fus_bn1s + C_, fus_bn1b + C_,
                                                             nullptr, rbh0, 256);
        k_conv3x3_part<<<gp, 256, 0, stream>>>(rbh0, fus_c2 + (size_t)C_ * C_ * 9, cpart, 16, 16);
        k_conv_fin<1><<<(tot + 255) / 256, 256, 0, stream>>>(cpart, fus_bn2s + C_, fus_bn2b + C_,
                                                             up0t, fus0, 256);
    }

    // ---- output head ----
    k_bn_gelu<<<(B_ * C_ * 256 + 255) / 256, 256, 0, stream>>>(fus0, op_bn0s, op_bn0b, hbuf, 256);
    {
        dim3 gp(B_ * (C_ / 4) * 4);
        int tot = B_ * C_ * 256;
        k_conv3x3_part<<<gp, 256, 0, stream>>>(hbuf, op_conv, cpart, 16, 16);
        k_conv_fin<2><<<(tot + 255) / 256, 256, 0, stream>>>(cpart, op_bn1s, op_bn1b,
                                                             x, (float*)d_out, 256);
    }
    (void)in_sizes; (void)n_in; (void)out_size;
}

// Round 17
// 2403.804 us; speedup vs baseline: 1.0523x; 1.0523x over previous
//
#include <hip/hip_runtime.h>
#include <hip/hip_bf16.h>
#include <math.h>

// ---------------------------------------------------------------------------
// HMABottleneck: B=4, C=512, H=W=16, DI=1024, K=4 dirs, N=16 states, R=32
// Round 17: SPL=4 wave scan, de-pressured: no A[16] (An per n), no a/b/Cv
// arrays (inline compose; reload B4/C4 + recompute exp in re-walk).
// Live-across-scan ~28 VGPR (r16 spilled: VGPR=64, 642MB scratch WRITE).
// Rest = r13/r16 baseline.
// ---------------------------------------------------------------------------

constexpr int B_  = 4;
constexpr int C_  = 512;
constexpr int DI_ = 1024;
constexpr int K_  = 4;
constexpr int N_  = 16;
constexpr int R_  = 32;
constexpr float BNS_ = 0.9999950000374997f;   // 1/sqrt(1+1e-5)

__device__ inline float geluf(float x) {
    return 0.5f * x * (1.0f + erff(x * 0.70710678118654752f));
}
__device__ inline float siluf(float x) {
    return x / (1.0f + expf(-x));
}
__device__ inline float softplusf(float x) {
    return fmaxf(x, 0.0f) + log1pf(expf(-fabsf(x)));
}

__device__ inline float blockReduceSum(float v, float* sd) {
    int tid = threadIdx.x;
    sd[tid] = v; __syncthreads();
    for (int s = blockDim.x / 2; s > 0; s >>= 1) {
        if (tid < s) sd[tid] += sd[tid + s];
        __syncthreads();
    }
    float r = sd[0]; __syncthreads();
    return r;
}

// --------------------------- LN over channels (NCHW -> (B*L, C)) -----------
__global__ void k_ln_nchw(const float* __restrict__ x, const float* __restrict__ w,
                          const float* __restrict__ b, float* __restrict__ out,
                          int L, float eps) {
    int row = blockIdx.x;            // b*L + l
    int bb = row / L, l = row % L;
    __shared__ float sd[256];
    __shared__ float srow[C_];
    const float* xp = x + (size_t)bb * C_ * L + l;
    float sum = 0.f;
    for (int c = threadIdx.x; c < C_; c += 256) { float v = xp[(size_t)c * L]; srow[c] = v; sum += v; }
    sum = blockReduceSum(sum, sd);
    float mu = sum / C_;
    float vs = 0.f;
    for (int c = threadIdx.x; c < C_; c += 256) { float d = srow[c] - mu; vs += d * d; }
    vs = blockReduceSum(vs, sd);
    float rstd = rsqrtf(vs / C_ + eps);
    float* op = out + (size_t)row * C_;
    for (int c = threadIdx.x; c < C_; c += 256) op[c] = (srow[c] - mu) * rstd * w[c] + b[c];
}

// --------------------------- tiled f32 GEMM: out = A (M,K) * Bw(N,K)^T -----
template <int EPI>
__global__ void k_gemm_nt(const float* __restrict__ A, const float* __restrict__ Bw,
                          float* __restrict__ Cout, int M, int Nn, int Kk,
                          const float* __restrict__ Res, int L) {
    const int BK = 16;
    __shared__ float As[BK][65];
    __shared__ float Bs[BK][65];
    int m0 = blockIdx.y * 64, n0 = blockIdx.x * 64;
    int tid = threadIdx.x;
    int tx = tid % 16, ty = tid / 16;
    float acc[4][4] = {};
    for (int k0 = 0; k0 < Kk; k0 += BK) {
        int mm = tid >> 2;
        int kk = (tid & 3) * 4;
        float4 va = *reinterpret_cast<const float4*>(A + (size_t)(m0 + mm) * Kk + k0 + kk);
        As[kk + 0][mm] = va.x; As[kk + 1][mm] = va.y; As[kk + 2][mm] = va.z; As[kk + 3][mm] = va.w;
        float4 vb = *reinterpret_cast<const float4*>(Bw + (size_t)(n0 + mm) * Kk + k0 + kk);
        Bs[kk + 0][mm] = vb.x; Bs[kk + 1][mm] = vb.y; Bs[kk + 2][mm] = vb.z; Bs[kk + 3][mm] = vb.w;
        __syncthreads();
#pragma unroll
        for (int k = 0; k < BK; ++k) {
            float a[4], b2[4];
#pragma unroll
            for (int i = 0; i < 4; i++) a[i] = As[k][ty + 16 * i];
#pragma unroll
            for (int j = 0; j < 4; j++) b2[j] = Bs[k][tx + 16 * j];
#pragma unroll
            for (int i = 0; i < 4; i++)
#pragma unroll
                for (int j = 0; j < 4; j++) acc[i][j] += a[i] * b2[j];
        }
        __syncthreads();
    }
#pragma unroll
    for (int i = 0; i < 4; i++) {
        int m = m0 + ty + 16 * i;
#pragma unroll
        for (int j = 0; j < 4; j++) {
            int n = n0 + tx + 16 * j;
            if (EPI == 0) {
                Cout[(size_t)m * Nn + n] = acc[i][j];
            } else {
                int bb = m / L, l = m % L;
                size_t o = ((size_t)bb * C_ + n) * L + l;
                Cout[o] = Res[o] + acc[i][j];
            }
        }
    }
}

// --------------------------- depthwise 3x3 (pad1) + bias + SiLU ------------
// writes xm (b,l,d) AND transposed xmT (b,d,l) for the wave-scan u-gather
__global__ void k_dwconv_silu(const float* __restrict__ xz, const float* __restrict__ cw,
                              const float* __restrict__ cb, float* __restrict__ xm,
                              float* __restrict__ xmT, int H, int W) {
    int L = H * W;
    int idx = blockIdx.x * 256 + threadIdx.x;            // (b, l, d) d fastest
    int total = B_ * L * DI_;
    if (idx >= total) return;
    int d = idx % DI_; int t = idx / DI_; int l = t % L; int bb = t / L;
    int h = l / W, w = l % W;
    float acc = cb[d];
    const float* wp = cw + d * 9;
#pragma unroll
    for (int dy = 0; dy < 3; dy++) {
        int hh = h + dy - 1;
        if ((unsigned)hh >= (unsigned)H) continue;
#pragma unroll
        for (int dx = 0; dx < 3; dx++) {
            int ww = w + dx - 1;
            if ((unsigned)ww >= (unsigned)W) continue;
            acc += xz[((size_t)bb * L + hh * W + ww) * (2 * DI_) + d] * wp[dy * 3 + dx];
        }
    }
    float v = siluf(acc);
    xm[idx] = v;
    xmT[((size_t)bb * DI_ + d) * L + l] = v;
}

// map (k,l) -> source flat index in row-major (h*W+w) order
__device__ inline int dir_src(int k, int l, int H, int W, int L) {
    int ll = (k >= 2) ? (L - 1 - l) : l;
    return (k & 1) ? ((ll % H) * W + ll / H) : ll;
}

// --------------------------- x_dbl (LDS row staging, 64 thr/block) ---------
__global__ void k_xdbl(const float* __restrict__ xm, const float* __restrict__ xproj,
                       float* __restrict__ xdbl, int H, int W) {
    int L = H * W;
    int blk = blockIdx.x;            // (b,k,l)
    int l = blk % L; int t = blk / L; int k = t % K_; int bb = t / K_;
    int src = dir_src(k, l, H, W, L);
    __shared__ float row[DI_];
    const float* xp = xm + ((size_t)bb * L + src) * DI_;
    for (int d = threadIdx.x; d < DI_; d += 64) row[d] = xp[d];
    __syncthreads();
    const float* wp = xproj + ((size_t)k * 64 + threadIdx.x) * DI_;
    float acc = 0.f;
    for (int d = 0; d < DI_; d++) acc += row[d] * wp[d];
    xdbl[((size_t)(bb * K_ + k) * 64 + threadIdx.x) * L + l] = acc;
}

// --------------------------- wave scan, SPL steps per lane (lean) ----------
// One 64-lane wave per (b,k,d); lane j owns steps [j*SPL, (j+1)*SPL).
// Per n: An = -exp(Alog[n]); compose aL,bL inline from transient B4 load;
// 6-step shfl_up inclusive scan; exclusive prefix; re-walk with RELOADED
// B4/C4 and RECOMPUTED exp(dl*An) (keeps live-across-scan set ~28 VGPR;
// r16's array version spilled: VGPR=64 + 642MB scratch WRITE).
// block = 256 threads = 4 waves (4 consecutive d); grid = B*K*(DI/4).
template <int LT>
__global__ void k_scan_wave(const float* __restrict__ xmT, const float* __restrict__ xdbl,
                            const float* __restrict__ dtw, const float* __restrict__ dtb,
                            const float* __restrict__ Alog, const float* __restrict__ Dp,
                            float* __restrict__ part, int H, int W) {
    constexpr int SPL = (LT == 256) ? 4 : 1;
    constexpr int CW  = (LT < 64) ? LT : 64;
    const int L = LT;
    int lane = threadIdx.x & 63;
    int wv = threadIdx.x >> 6;
    int blk = blockIdx.x;                // (bb, k, dq)
    const int ndq = DI_ / 4;
    int dq = blk % ndq; int t2 = blk / ndq; int k = t2 % K_; int bb = t2 / K_;
    int d = dq * 4 + wv;

    const float* wrow = dtw + ((size_t)k * DI_ + d) * R_;     // wave-uniform
    const float* al   = Alog + ((size_t)k * DI_ + d) * N_;    // wave-uniform
    float bias = dtb[k * DI_ + d];
    float Dv   = Dp[k * DI_ + d];

    const float* bc = xdbl + (size_t)(bb * K_ + k) * 64 * L;
    const float* ut = xmT + ((size_t)bb * DI_ + d) * L;
    float* yb = part + (size_t)(bb * K_ + k) * L * DI_ + d;

    int lj = lane < CW ? lane : CW - 1;      // lanes >= CW duplicate last step
    int base = lj * SPL;

    float dl[SPL], du[SPL], uu[SPL], y[SPL];
    {
        float accv[SPL];
#pragma unroll
        for (int i = 0; i < SPL; i++) accv[i] = bias;
#pragma unroll
        for (int r = 0; r < R_; r++) {
            float wr = wrow[r];
            if constexpr (SPL == 4) {
                float4 d4 = *reinterpret_cast<const float4*>(bc + (size_t)r * L + base);
                accv[0] += d4.x * wr; accv[1] += d4.y * wr;
                accv[2] += d4.z * wr; accv[3] += d4.w * wr;
            } else {
                accv[0] += bc[(size_t)r * L + base] * wr;
            }
        }
#pragma unroll
        for (int i = 0; i < SPL; i++) {
            int src = dir_src(k, base + i, H, W, L);
            dl[i] = softplusf(accv[i]);
            uu[i] = ut[src];
            du[i] = dl[i] * uu[i];
            y[i] = 0.f;
        }
    }

#pragma unroll
    for (int n = 0; n < N_; n++) {
        float An = -expf(al[n]);
        float aL, bL;
        if constexpr (SPL == 4) {
            float4 B4 = *reinterpret_cast<const float4*>(bc + (size_t)(R_ + n) * L + base);
            float a0 = expf(dl[0] * An);
            aL = a0; bL = du[0] * B4.x;
            float a1 = expf(dl[1] * An);
            bL = a1 * bL + du[1] * B4.y; aL = a1 * aL;
            float a2 = expf(dl[2] * An);
            bL = a2 * bL + du[2] * B4.z; aL = a2 * aL;
            float a3 = expf(dl[3] * An);
            bL = a3 * bL + du[3] * B4.w; aL = a3 * aL;
        } else {
            aL = expf(dl[0] * An);
            bL = du[0] * bc[(size_t)(R_ + n) * L + base];
        }
#pragma unroll
        for (int off = 1; off < CW; off <<= 1) {
            float ap = __shfl_up(aL, off);
            float bp = __shfl_up(bL, off);
            if (lane >= off) { bL = aL * bp + bL; aL = aL * ap; }
        }
        float hin = __shfl_up(bL, 1);
        if (lane == 0) hin = 0.f;
        if constexpr (SPL == 4) {
            float4 B4 = *reinterpret_cast<const float4*>(bc + (size_t)(R_ + n) * L + base);
            float4 C4 = *reinterpret_cast<const float4*>(bc + (size_t)(R_ + N_ + n) * L + base);
            float h = hin;
            h = expf(dl[0] * An) * h + du[0] * B4.x; y[0] += h * C4.x;
            h = expf(dl[1] * An) * h + du[1] * B4.y; y[1] += h * C4.y;
            h = expf(dl[2] * An) * h + du[2] * B4.z; y[2] += h * C4.z;
            h = expf(dl[3] * An) * h + du[3] * B4.w; y[3] += h * C4.w;
        } else {
            float h = expf(dl[0] * An) * hin + du[0] * bc[(size_t)(R_ + n) * L + base];
            y[0] += h * bc[(size_t)(R_ + N_ + n) * L + base];
        }
    }

    if (lane < CW) {
#pragma unroll
        for (int i = 0; i < SPL; i++) {
            int src = dir_src(k, base + i, H, W, L);
            yb[(size_t)src * DI_] = y[i] + Dv * uu[i];
        }
    }
}

// --------------------------- merge 4 direction partials --------------------
__global__ void k_merge4(const float* __restrict__ part, float* __restrict__ ybuf,
                         int L) {
    int idx = blockIdx.x * 256 + threadIdx.x;    // (b,l,d)
    int total = B_ * L * DI_;
    if (idx >= total) return;
    int d = idx % DI_; int t = idx / DI_; int l = t % L; int bb = t / L;
    size_t s = ((size_t)bb * K_ * L + l) * DI_ + d;
    float v = part[s] + part[s + (size_t)L * DI_] + part[s + (size_t)2 * L * DI_]
            + part[s + (size_t)3 * L * DI_];
    ybuf[idx] = v;
}

// --------------------------- LN(y) * silu(z) -> t (B*L, DI) ----------------
__global__ void k_ln_silu(const float* __restrict__ y, const float* __restrict__ xz,
                          const float* __restrict__ onw, const float* __restrict__ onb,
                          float* __restrict__ tout) {
    int row = blockIdx.x;            // b*L + l
    __shared__ float sd[256];
    __shared__ float srow[DI_];
    const float* yp = y + (size_t)row * DI_;
    float sum = 0.f;
    for (int d = threadIdx.x; d < DI_; d += 256) { float v = yp[d]; srow[d] = v; sum += v; }
    sum = blockReduceSum(sum, sd);
    float mu = sum / DI_;
    float vs = 0.f;
    for (int d = threadIdx.x; d < DI_; d += 256) { float dv = srow[d] - mu; vs += dv * dv; }
    vs = blockReduceSum(vs, sd);
    float rstd = rsqrtf(vs / DI_ + 1e-5f);
    const float* zp = xz + (size_t)row * 2 * DI_ + DI_;
    float* tp = tout + (size_t)row * DI_;
    for (int d = threadIdx.x; d < DI_; d += 256) {
        float zn = zp[d];
        tp[d] = ((srow[d] - mu) * rstd * onw[d] + onb[d]) * siluf(zn);
    }
}

// --------------------------- downsample: dw conv s2 + BN + GELU ------------
__global__ void k_dwconv_s2_bn_gelu(const float* __restrict__ x, const float* __restrict__ dw,
                                    const float* __restrict__ bns, const float* __restrict__ bnb,
                                    float* __restrict__ out, int Hi, int Wi) {
    int Ho = Hi / 2, Wo = Wi / 2;
    int idx = blockIdx.x * 256 + threadIdx.x;            // (b,c,ho,wo)
    int total = B_ * C_ * Ho * Wo;
    if (idx >= total) return;
    int wo = idx % Wo; int t = idx / Wo; int ho = t % Ho; t /= Ho; int c = t % C_; int bb = t / C_;
    float acc = 0.f;
    const float* xp = x + ((size_t)bb * C_ + c) * Hi * Wi;
    const float* wp = dw + c * 9;
#pragma unroll
    for (int dy = 0; dy < 3; dy++) {
        int ih = ho * 2 + dy - 1;
        if ((unsigned)ih >= (unsigned)Hi) continue;
#pragma unroll
        for (int dx = 0; dx < 3; dx++) {
            int iw = wo * 2 + dx - 1;
            if ((unsigned)iw >= (unsigned)Wi) continue;
            acc += xp[ih * Wi + iw] * wp[dy * 3 + dx];
        }
    }
    acc = acc * (bns[c] * BNS_) + bnb[c];
    out[idx] = geluf(acc);
}

// --------------------------- pointwise 1x1 conv + BN + GELU ----------------
__global__ void k_pwconv_bn_gelu(const float* __restrict__ x, const float* __restrict__ pw,
                                 const float* __restrict__ bns, const float* __restrict__ bnb,
                                 float* __restrict__ out, int L) {
    int idx = blockIdx.x * 256 + threadIdx.x;            // (b,co,l)
    int total = B_ * C_ * L;
    if (idx >= total) return;
    int l = idx % L; int t = idx / L; int co = t % C_; int bb = t / C_;
    const float* xp = x + (size_t)bb * C_ * L + l;
    const float* wp = pw + (size_t)co * C_;
    float acc = 0.f;
    for (int ci = 0; ci < C_; ci++) acc += xp[(size_t)ci * L] * wp[ci];
    acc = acc * (bns[co] * BNS_) + bnb[co];
    out[idx] = geluf(acc);
}

// --------------------------- 3x3 conv, split-C partial (r11 body) ----------
__global__ void k_conv3x3_part(const float* __restrict__ x, const float* __restrict__ wgt,
                               float* __restrict__ partial, int H, int W) {
    const int COB = 4, CH = 4, SPLIT = 4;
    const int CSEG = C_ / SPLIT;         // 128
    int L = H * W;                       // == blockDim.x
    int t = threadIdx.x;
    int h = t / W, w = t % W;
    int blk = blockIdx.x;
    int s = blk % SPLIT; int t2 = blk / SPLIT;
    int ng = C_ / COB;
    int cg = t2 % ng; int bb = t2 / ng;
    int co0 = cg * COB;
    __shared__ float sp[2][CH * 256];
    float acc[COB];
#pragma unroll
    for (int j = 0; j < COB; j++) acc[j] = 0.f;
    const float* xb = x + (size_t)bb * C_ * L;
    int cbeg = s * CSEG;
    float4 pre = *reinterpret_cast<const float4*>(xb + (size_t)cbeg * L + 4 * t);
    int p = 0;
    for (int c0 = cbeg; c0 < cbeg + CSEG; c0 += CH) {
        *reinterpret_cast<float4*>(&sp[p][4 * t]) = pre;
        __syncthreads();
        if (c0 + CH < cbeg + CSEG)
            pre = *reinterpret_cast<const float4*>(xb + (size_t)(c0 + CH) * L + 4 * t);
#pragma unroll 1
        for (int ci = 0; ci < CH; ci++) {
            const float* pl = &sp[p][ci * L];
            float v[9];
#pragma unroll
            for (int dy = 0; dy < 3; dy++) {
                int hh = h + dy - 1;
                bool hok = (unsigned)hh < (unsigned)H;
#pragma unroll
                for (int dx = 0; dx < 3; dx++) {
                    int ww = w + dx - 1;
                    bool ok = hok && ((unsigned)ww < (unsigned)W);
                    v[dy * 3 + dx] = ok ? pl[hh * W + ww] : 0.f;
                }
            }
            const float* wr = wgt + ((size_t)co0 * C_ + c0 + ci) * 9;
#pragma unroll
            for (int j = 0; j < COB; j++) {
                const float* wj = wr + (size_t)j * C_ * 9;
                float a = acc[j];
                a += v[0] * wj[0] + v[1] * wj[1] + v[2] * wj[2];
                a += v[3] * wj[3] + v[4] * wj[4] + v[5] * wj[5];
                a += v[6] * wj[6] + v[7] * wj[7] + v[8] * wj[8];
                acc[j] = a;
            }
        }
        p ^= 1;
    }
    size_t base = (size_t)s * B_ * C_ * L;
#pragma unroll
    for (int j = 0; j < COB; j++)
        partial[base + ((size_t)bb * C_ + co0 + j) * L + t] = acc[j];
}

// --------------------------- conv finish: sum 4 partials + epilogue --------
template <int MODE>
__global__ void k_conv_fin(const float* __restrict__ part4, const float* __restrict__ bns,
                           const float* __restrict__ bnb, const float* __restrict__ res,
                           float* __restrict__ out, int L) {
    int idx = blockIdx.x * 256 + threadIdx.x;    // (b,c,l)
    int total = B_ * C_ * L;
    if (idx >= total) return;
    int c = (idx / L) % C_;
    size_t T = (size_t)total;
    float a = part4[idx] + part4[idx + T] + part4[idx + 2 * T] + part4[idx + 3 * T];
    a = a * (bns[c] * BNS_) + bnb[c];
    if (MODE == 0) out[idx] = geluf(a);
    else if (MODE == 1) out[idx] = geluf(a + res[idx]);
    else out[idx] = geluf(a) + res[idx];
}

// --------------------------- bilinear up + skip add ------------------------
__global__ void k_up_add(const float* __restrict__ low, const float* __restrict__ skip,
                         float* __restrict__ out, int Hi, int Wi, int Ho, int Wo) {
    int idx = blockIdx.x * 256 + threadIdx.x;            // (b,c,ho,wo)
    int total = B_ * C_ * Ho * Wo;
    if (idx >= total) return;
    int wo = idx % Wo; int t = idx / Wo; int ho = t % Ho; t /= Ho; int c = t % C_; int bb = t / C_;
    float fy = (float)ho * (float)(Hi - 1) / (float)(Ho - 1);
    float fx = (float)wo * (float)(Wi - 1) / (float)(Wo - 1);
    int y0 = (int)floorf(fy); int y1 = min(y0 + 1, Hi - 1); float wy = fy - (float)y0;
    int x0 = (int)floorf(fx); int x1 = min(x0 + 1, Wi - 1); float wx = fx - (float)x0;
    const float* lp = low + ((size_t)bb * C_ + c) * Hi * Wi;
    float g0 = lp[y0 * Wi + x0] * (1.f - wy) + lp[y1 * Wi + x0] * wy;
    float g1 = lp[y0 * Wi + x1] * (1.f - wy) + lp[y1 * Wi + x1] * wy;
    out[idx] = skip[idx] + g0 * (1.f - wx) + g1 * wx;
}

// --------------------------- BN + GELU elementwise -------------------------
__global__ void k_bn_gelu(const float* __restrict__ x, const float* __restrict__ s,
                          const float* __restrict__ b, float* __restrict__ out, int L) {
    int idx = blockIdx.x * 256 + threadIdx.x;            // (b,c,l)
    int total = B_ * C_ * L;
    if (idx >= total) return;
    int t = idx / L; int c = t % C_;
    out[idx] = geluf(x[idx] * (s[c] * BNS_) + b[c]);
}

// --------------------------- diagnostic fill (f32) -------------------------
__global__ void k_fill_out(float* o, int n, float v) {
    int i = blockIdx.x * 256 + threadIdx.x;
    if (i < n) o[i] = v;
}

// ===========================================================================
struct VssW {
    const float *lnw, *lnb, *inproj, *convw, *convb, *xproj, *dtw, *dtb, *Alog, *D, *onw, *onb, *outproj;
};

static void run_vss(const float* xc_in, float* xc_out, const VssW& p, int H, int W,
                    float* xln, float* xz, float* xm, float* xmT, float* xdbl,
                    float* part, float* ybuf, float* tbuf, hipStream_t stream) {
    int L = H * W, M = B_ * L;
    k_ln_nchw<<<M, 256, 0, stream>>>(xc_in, p.lnw, p.lnb, xln, L, 1e-6f);
    {
        dim3 g(2 * DI_ / 64, M / 64);
        k_gemm_nt<0><<<g, 256, 0, stream>>>(xln, p.inproj, xz, M, 2 * DI_, C_, nullptr, L);
    }
    {
        int tot = B_ * L * DI_;
        k_dwconv_silu<<<(tot + 255) / 256, 256, 0, stream>>>(xz, p.convw, p.convb, xm, xmT, H, W);
    }
    k_xdbl<<<B_ * K_ * L, 64, 0, stream>>>(xm, p.xproj, xdbl, H, W);
    {
        int g = B_ * K_ * (DI_ / 4);
        if (L == 256)
            k_scan_wave<256><<<g, 256, 0, stream>>>(xmT, xdbl, p.dtw, p.dtb, p.Alog, p.D, part, H, W);
        else if (L == 64)
            k_scan_wave<64><<<g, 256, 0, stream>>>(xmT, xdbl, p.dtw, p.dtb, p.Alog, p.D, part, H, W);
        else
            k_scan_wave<16><<<g, 256, 0, stream>>>(xmT, xdbl, p.dtw, p.dtb, p.Alog, p.D, part, H, W);
    }
    {
        int tot = B_ * L * DI_;
        k_merge4<<<(tot + 255) / 256, 256, 0, stream>>>(part, ybuf, L);
    }
    k_ln_silu<<<M, 256, 0, stream>>>(ybuf, xz, p.onw, p.onb, tbuf);
    {
        dim3 g(C_ / 64, M / 64);
        k_gemm_nt<1><<<g, 256, 0, stream>>>(tbuf, p.outproj, xc_out, M, C_, DI_, xc_in, L);
    }
}

extern "C" void kernel_launch(void* const* d_in, const int* in_sizes, int n_in,
                              void* d_out, int out_size, void* d_ws, size_t ws_size,
                              hipStream_t stream) {
    constexpr size_t NEED_FLOATS = 12124160;
    constexpr size_t NEED_BYTES  = NEED_FLOATS * 4;   // 48,496,640
    if (ws_size < NEED_BYTES) {
        k_fill_out<<<(out_size + 255) / 256, 256, 0, stream>>>((float*)d_out, out_size, 0.0f);
        return;
    }

    const float* x        = (const float*)d_in[0];
    const float* lnw      = (const float*)d_in[1];
    const float* lnb      = (const float*)d_in[2];
    const float* inproj   = (const float*)d_in[3];
    const float* convw    = (const float*)d_in[4];
    const float* convb    = (const float*)d_in[5];
    const float* xprojp   = (const float*)d_in[6];
    const float* dtwp     = (const float*)d_in[7];
    const float* dtbp     = (const float*)d_in[8];
    const float* Alogp    = (const float*)d_in[9];
    const float* Dpp      = (const float*)d_in[10];
    const float* onwp     = (const float*)d_in[11];
    const float* onbp     = (const float*)d_in[12];
    const float* outprojp = (const float*)d_in[13];
    const float* ds_dw    = (const float*)d_in[14];
    const float* ds_bn1s  = (const float*)d_in[15];
    const float* ds_bn1b  = (const float*)d_in[16];
    const float* ds_pw    = (const float*)d_in[17];
    const float* ds_bn2s  = (const float*)d_in[18];
    const float* ds_bn2b  = (const float*)d_in[19];
    const float* fus_c1   = (const float*)d_in[20];
    const float* fus_bn1s = (const float*)d_in[21];
    const float* fus_bn1b = (const float*)d_in[22];
    const float* fus_c2   = (const float*)d_in[23];
    const float* fus_bn2s = (const float*)d_in[24];
    const float* fus_bn2b = (const float*)d_in[25];
    const float* op_bn0s  = (const float*)d_in[26];
    const float* op_bn0b  = (const float*)d_in[27];
    const float* op_conv  = (const float*)d_in[28];
    const float* op_bn1s  = (const float*)d_in[29];
    const float* op_bn1b  = (const float*)d_in[30];

    float* ws = (float*)d_ws;
    float* xln   = ws;                    // 524288
    float* xz    = ws + 524288;           // 2097152
    float* xm    = ws + 2621440;          // 1048576
    float* xdbl  = ws + 3670016;          // 262144
    float* ybuf  = ws + 3932160;          // 1048576
    float* part  = ws + 4980736;          // 4194304
    float* tbuf  = part;                  // alias: part dead before ln_silu
    float* t_a   = ws + 9175040;          // 524288
    float* xr    = ws + 9699328;          // 524288
    float* p1    = ws + 10223616;         // 131072
    float* p2    = ws + 10354688;         // 32768
    float* proc0 = ws + 10387456;         // 524288
    float* proc1 = ws + 10911744;         // 131072
    float* proc2 = ws + 11042816;         // 32768
    float* xmT   = ws + 11075584;         // 1048576 (transposed xm)
    float* p1pre = xz;                    // 131072
    float* p2pre = xz + 131072;           // 32768
    float* up1t  = xln;                   // 131072
    float* rbh1  = xln + 131072;          // 131072
    float* fus1  = xln + 262144;          // 131072
    float* up0t  = xm;                    // 524288
    float* rbh0  = part;                  // 524288
    float* fus0  = part + 524288;         // 524288
    float* hbuf  = part + 1048576;        // 524288
    float* cpart = part + 1572864;        // 2097152 (4 conv partials)

    VssW vp[5];
    for (int i = 0; i < 5; i++) {
        vp[i].lnw     = lnw + (size_t)i * C_;
        vp[i].lnb     = lnb + (size_t)i * C_;
        vp[i].inproj  = inproj + (size_t)i * 2 * DI_ * C_;
        vp[i].convw   = convw + (size_t)i * DI_ * 9;
        vp[i].convb   = convb + (size_t)i * DI_;
        vp[i].xproj   = xprojp + (size_t)i * K_ * 64 * DI_;
        vp[i].dtw     = dtwp + (size_t)i * K_ * DI_ * R_;
        vp[i].dtb     = dtbp + (size_t)i * K_ * DI_;
        vp[i].Alog    = Alogp + (size_t)i * K_ * DI_ * N_;
        vp[i].D       = Dpp + (size_t)i * K_ * DI_;
        vp[i].onw     = onwp + (size_t)i * DI_;
        vp[i].onb     = onbp + (size_t)i * DI_;
        vp[i].outproj = outprojp + (size_t)i * C_ * DI_;
    }

    // ---- stem: two VSS at 16x16 ----
    run_vss(x,   t_a, vp[0], 16, 16, xln, xz, xm, xmT, xdbl, part, ybuf, tbuf, stream);
    run_vss(t_a, xr,  vp[1], 16, 16, xln, xz, xm, xmT, xdbl, part, ybuf, tbuf, stream);

    // ---- down 0: 16 -> 8 ----
    k_dwconv_s2_bn_gelu<<<(B_ * C_ * 64 + 255) / 256, 256, 0, stream>>>(
        xr, ds_dw, ds_bn1s, ds_bn1b, p1pre, 16, 16);
    k_pwconv_bn_gelu<<<(B_ * C_ * 64 + 255) / 256, 256, 0, stream>>>(
        p1pre, ds_pw, ds_bn2s, ds_bn2b, p1, 64);
    // ---- down 1: 8 -> 4 ----
    k_dwconv_s2_bn_gelu<<<(B_ * C_ * 16 + 255) / 256, 256, 0, stream>>>(
        p1, ds_dw + (size_t)C_ * 9, ds_bn1s + C_, ds_bn1b + C_, p2pre, 8, 8);
    k_pwconv_bn_gelu<<<(B_ * C_ * 16 + 255) / 256, 256, 0, stream>>>(
        p2pre, ds_pw + (size_t)C_ * C_, ds_bn2s + C_, ds_bn2b + C_, p2, 16);

    // ---- per-scale VSS ----
    run_vss(xr, proc0, vp[2], 16, 16, xln, xz, xm, xmT, xdbl, part, ybuf, tbuf, stream);
    run_vss(p1, proc1, vp[3],  8,  8, xln, xz, xm, xmT, xdbl, part, ybuf, tbuf, stream);
    run_vss(p2, proc2, vp[4],  4,  4, xln, xz, xm, xmT, xdbl, part, ybuf, tbuf, stream);

    // ---- fuse i=1: up(proc2: 4->8) + proc1, resblk j=0 ----
    k_up_add<<<(B_ * C_ * 64 + 255) / 256, 256, 0, stream>>>(proc2, proc1, up1t, 4, 4, 8, 8);
    {
        dim3 gp(B_ * (C_ / 4) * 4);
        int tot = B_ * C_ * 64;
        k_conv3x3_part<<<gp, 64, 0, stream>>>(up1t, fus_c1, cpart, 8, 8);
        k_conv_fin<0><<<(tot + 255) / 256, 256, 0, stream>>>(cpart, fus_bn1s, fus_bn1b,
                                                             nullptr, rbh1, 64);
        k_conv3x3_part<<<gp, 64, 0, stream>>>(rbh1, fus_c2, cpart, 8, 8);
        k_conv_fin<1><<<(tot + 255) / 256, 256, 0, stream>>>(cpart, fus_bn2s, fus_bn2b,
                                                             up1t, fus1, 64);
    }
    // ---- fuse i=0: up(fus1: 8->16) + proc0, resblk j=1 ----
    k_up_add<<<(B_ * C_ * 256 + 255) / 256, 256, 0, stream>>>(fus1, proc0, up0t, 8, 8, 16, 16);
    {
        dim3 gp(B_ * (C_ / 4) * 4);
        int tot = B_ * C_ * 256;
        k_conv3x3_part<<<gp, 256, 0, stream>>>(up0t, fus_c1 + (size_t)C_ * C_ * 9, cpart, 16, 16);
        k_conv_fin<0><<<(tot + 255) / 256, 256, 0, stream>>>(cpart, fus_bn1s + C_, fus_bn1b + C_,
                                                             nullptr, rbh0, 256);
        k_conv3x3_part<<<gp, 256, 0, stream>>>(rbh0, fus_c2 + (size_t)C_ * C_ * 9, cpart, 16, 16);
        k_conv_fin<1><<<(tot + 255) / 256, 256, 0, stream>>>(cpart, fus_bn2s + C_, fus_bn2b + C_,
                                                             up0t, fus0, 256);
    }

    // ---- output head ----
    k_bn_gelu<<<(B_ * C_ * 256 + 255) / 256, 256, 0, stream>>>(fus0, op_bn0s, op_bn0b, hbuf, 256);
    {
        dim3 gp(B_ * (C_ / 4) * 4);
        int tot = B_ * C_ * 256;
        k_conv3x3_part<<<gp, 256, 0, stream>>>(hbuf, op_conv, cpart, 16, 16);
        k_conv_fin<2><<<(tot + 255) / 256, 256, 0, stream>>>(cpart, op_bn1s, op_bn1b,
                                                             x, (float*)d_out, 256);
    }
    (void)in_sizes; (void)n_in; (void)out_size;
}

// Round 18
// 1981.157 us; speedup vs baseline: 1.2768x; 1.2133x over previous
//
#include <hip/hip_runtime.h>
#include <hip/hip_bf16.h>
#include <math.h>

// ---------------------------------------------------------------------------
// HMABottleneck: B=4, C=512, H=W=16, DI=1024, K=4 dirs, N=16 states, R=32
// Round 18: r17 scan + "#pragma unroll 1" on the n-loop. r16/r17 spills were
// the UNROLLED n-loop hoisting 32 float4 loads (128 VGPRs in flight).
// unroll 1 blocks cross-iteration hoisting. Rest identical to r17.
// ---------------------------------------------------------------------------

constexpr int B_  = 4;
constexpr int C_  = 512;
constexpr int DI_ = 1024;
constexpr int K_  = 4;
constexpr int N_  = 16;
constexpr int R_  = 32;
constexpr float BNS_ = 0.9999950000374997f;   // 1/sqrt(1+1e-5)

__device__ inline float geluf(float x) {
    return 0.5f * x * (1.0f + erff(x * 0.70710678118654752f));
}
__device__ inline float siluf(float x) {
    return x / (1.0f + expf(-x));
}
__device__ inline float softplusf(float x) {
    return fmaxf(x, 0.0f) + log1pf(expf(-fabsf(x)));
}

__device__ inline float blockReduceSum(float v, float* sd) {
    int tid = threadIdx.x;
    sd[tid] = v; __syncthreads();
    for (int s = blockDim.x / 2; s > 0; s >>= 1) {
        if (tid < s) sd[tid] += sd[tid + s];
        __syncthreads();
    }
    float r = sd[0]; __syncthreads();
    return r;
}

// --------------------------- LN over channels (NCHW -> (B*L, C)) -----------
__global__ void k_ln_nchw(const float* __restrict__ x, const float* __restrict__ w,
                          const float* __restrict__ b, float* __restrict__ out,
                          int L, float eps) {
    int row = blockIdx.x;            // b*L + l
    int bb = row / L, l = row % L;
    __shared__ float sd[256];
    __shared__ float srow[C_];
    const float* xp = x + (size_t)bb * C_ * L + l;
    float sum = 0.f;
    for (int c = threadIdx.x; c < C_; c += 256) { float v = xp[(size_t)c * L]; srow[c] = v; sum += v; }
    sum = blockReduceSum(sum, sd);
    float mu = sum / C_;
    float vs = 0.f;
    for (int c = threadIdx.x; c < C_; c += 256) { float d = srow[c] - mu; vs += d * d; }
    vs = blockReduceSum(vs, sd);
    float rstd = rsqrtf(vs / C_ + eps);
    float* op = out + (size_t)row * C_;
    for (int c = threadIdx.x; c < C_; c += 256) op[c] = (srow[c] - mu) * rstd * w[c] + b[c];
}

// --------------------------- tiled f32 GEMM: out = A (M,K) * Bw(N,K)^T -----
template <int EPI>
__global__ void k_gemm_nt(const float* __restrict__ A, const float* __restrict__ Bw,
                          float* __restrict__ Cout, int M, int Nn, int Kk,
                          const float* __restrict__ Res, int L) {
    const int BK = 16;
    __shared__ float As[BK][65];
    __shared__ float Bs[BK][65];
    int m0 = blockIdx.y * 64, n0 = blockIdx.x * 64;
    int tid = threadIdx.x;
    int tx = tid % 16, ty = tid / 16;
    float acc[4][4] = {};
    for (int k0 = 0; k0 < Kk; k0 += BK) {
        int mm = tid >> 2;
        int kk = (tid & 3) * 4;
        float4 va = *reinterpret_cast<const float4*>(A + (size_t)(m0 + mm) * Kk + k0 + kk);
        As[kk + 0][mm] = va.x; As[kk + 1][mm] = va.y; As[kk + 2][mm] = va.z; As[kk + 3][mm] = va.w;
        float4 vb = *reinterpret_cast<const float4*>(Bw + (size_t)(n0 + mm) * Kk + k0 + kk);
        Bs[kk + 0][mm] = vb.x; Bs[kk + 1][mm] = vb.y; Bs[kk + 2][mm] = vb.z; Bs[kk + 3][mm] = vb.w;
        __syncthreads();
#pragma unroll
        for (int k = 0; k < BK; ++k) {
            float a[4], b2[4];
#pragma unroll
            for (int i = 0; i < 4; i++) a[i] = As[k][ty + 16 * i];
#pragma unroll
            for (int j = 0; j < 4; j++) b2[j] = Bs[k][tx + 16 * j];
#pragma unroll
            for (int i = 0; i < 4; i++)
#pragma unroll
                for (int j = 0; j < 4; j++) acc[i][j] += a[i] * b2[j];
        }
        __syncthreads();
    }
#pragma unroll
    for (int i = 0; i < 4; i++) {
        int m = m0 + ty + 16 * i;
#pragma unroll
        for (int j = 0; j < 4; j++) {
            int n = n0 + tx + 16 * j;
            if (EPI == 0) {
                Cout[(size_t)m * Nn + n] = acc[i][j];
            } else {
                int bb = m / L, l = m % L;
                size_t o = ((size_t)bb * C_ + n) * L + l;
                Cout[o] = Res[o] + acc[i][j];
            }
        }
    }
}

// --------------------------- depthwise 3x3 (pad1) + bias + SiLU ------------
// writes xm (b,l,d) AND transposed xmT (b,d,l) for the wave-scan u-gather
__global__ void k_dwconv_silu(const float* __restrict__ xz, const float* __restrict__ cw,
                              const float* __restrict__ cb, float* __restrict__ xm,
                              float* __restrict__ xmT, int H, int W) {
    int L = H * W;
    int idx = blockIdx.x * 256 + threadIdx.x;            // (b, l, d) d fastest
    int total = B_ * L * DI_;
    if (idx >= total) return;
    int d = idx % DI_; int t = idx / DI_; int l = t % L; int bb = t / L;
    int h = l / W, w = l % W;
    float acc = cb[d];
    const float* wp = cw + d * 9;
#pragma unroll
    for (int dy = 0; dy < 3; dy++) {
        int hh = h + dy - 1;
        if ((unsigned)hh >= (unsigned)H) continue;
#pragma unroll
        for (int dx = 0; dx < 3; dx++) {
            int ww = w + dx - 1;
            if ((unsigned)ww >= (unsigned)W) continue;
            acc += xz[((size_t)bb * L + hh * W + ww) * (2 * DI_) + d] * wp[dy * 3 + dx];
        }
    }
    float v = siluf(acc);
    xm[idx] = v;
    xmT[((size_t)bb * DI_ + d) * L + l] = v;
}

// map (k,l) -> source flat index in row-major (h*W+w) order
__device__ inline int dir_src(int k, int l, int H, int W, int L) {
    int ll = (k >= 2) ? (L - 1 - l) : l;
    return (k & 1) ? ((ll % H) * W + ll / H) : ll;
}

// --------------------------- x_dbl (LDS row staging, 64 thr/block) ---------
__global__ void k_xdbl(const float* __restrict__ xm, const float* __restrict__ xproj,
                       float* __restrict__ xdbl, int H, int W) {
    int L = H * W;
    int blk = blockIdx.x;            // (b,k,l)
    int l = blk % L; int t = blk / L; int k = t % K_; int bb = t / K_;
    int src = dir_src(k, l, H, W, L);
    __shared__ float row[DI_];
    const float* xp = xm + ((size_t)bb * L + src) * DI_;
    for (int d = threadIdx.x; d < DI_; d += 64) row[d] = xp[d];
    __syncthreads();
    const float* wp = xproj + ((size_t)k * 64 + threadIdx.x) * DI_;
    float acc = 0.f;
    for (int d = 0; d < DI_; d++) acc += row[d] * wp[d];
    xdbl[((size_t)(bb * K_ + k) * 64 + threadIdx.x) * L + l] = acc;
}

// --------------------------- wave scan, SPL steps per lane (lean) ----------
// One 64-lane wave per (b,k,d); lane j owns steps [j*SPL, (j+1)*SPL).
// Per n: An = -exp(Alog[n]); compose aL,bL inline from transient B4 load;
// shfl_up inclusive scan; exclusive prefix; re-walk with reloaded B4/C4 and
// recomputed exp. "#pragma unroll 1" on the n-loop: the fully-unrolled loop
// hoisted 32 float4 loads -> 64-VGPR spill (r16/r17 post-mortems).
// block = 256 threads = 4 waves (4 consecutive d); grid = B*K*(DI/4).
template <int LT>
__global__ void k_scan_wave(const float* __restrict__ xmT, const float* __restrict__ xdbl,
                            const float* __restrict__ dtw, const float* __restrict__ dtb,
                            const float* __restrict__ Alog, const float* __restrict__ Dp,
                            float* __restrict__ part, int H, int W) {
    constexpr int SPL = (LT == 256) ? 4 : 1;
    constexpr int CW  = (LT < 64) ? LT : 64;
    const int L = LT;
    int lane = threadIdx.x & 63;
    int wv = threadIdx.x >> 6;
    int blk = blockIdx.x;                // (bb, k, dq)
    const int ndq = DI_ / 4;
    int dq = blk % ndq; int t2 = blk / ndq; int k = t2 % K_; int bb = t2 / K_;
    int d = dq * 4 + wv;

    const float* wrow = dtw + ((size_t)k * DI_ + d) * R_;     // wave-uniform
    const float* al   = Alog + ((size_t)k * DI_ + d) * N_;    // wave-uniform
    float bias = dtb[k * DI_ + d];
    float Dv   = Dp[k * DI_ + d];

    const float* bc = xdbl + (size_t)(bb * K_ + k) * 64 * L;
    const float* ut = xmT + ((size_t)bb * DI_ + d) * L;
    float* yb = part + (size_t)(bb * K_ + k) * L * DI_ + d;

    int lj = lane < CW ? lane : CW - 1;      // lanes >= CW duplicate last step
    int base = lj * SPL;

    float dl[SPL], du[SPL], uu[SPL], y[SPL];
    {
        float accv[SPL];
#pragma unroll
        for (int i = 0; i < SPL; i++) accv[i] = bias;
#pragma unroll 8
        for (int r = 0; r < R_; r++) {
            float wr = wrow[r];
            if constexpr (SPL == 4) {
                float4 d4 = *reinterpret_cast<const float4*>(bc + (size_t)r * L + base);
                accv[0] += d4.x * wr; accv[1] += d4.y * wr;
                accv[2] += d4.z * wr; accv[3] += d4.w * wr;
            } else {
                accv[0] += bc[(size_t)r * L + base] * wr;
            }
        }
#pragma unroll
        for (int i = 0; i < SPL; i++) {
            int src = dir_src(k, base + i, H, W, L);
            dl[i] = softplusf(accv[i]);
            uu[i] = ut[src];
            du[i] = dl[i] * uu[i];
            y[i] = 0.f;
        }
    }

#pragma unroll 1
    for (int n = 0; n < N_; n++) {
        float An = -expf(al[n]);
        float aL, bL;
        if constexpr (SPL == 4) {
            float4 B4 = *reinterpret_cast<const float4*>(bc + (size_t)(R_ + n) * L + base);
            float a0 = expf(dl[0] * An);
            aL = a0; bL = du[0] * B4.x;
            float a1 = expf(dl[1] * An);
            bL = a1 * bL + du[1] * B4.y; aL = a1 * aL;
            float a2 = expf(dl[2] * An);
            bL = a2 * bL + du[2] * B4.z; aL = a2 * aL;
            float a3 = expf(dl[3] * An);
            bL = a3 * bL + du[3] * B4.w; aL = a3 * aL;
        } else {
            aL = expf(dl[0] * An);
            bL = du[0] * bc[(size_t)(R_ + n) * L + base];
        }
#pragma unroll
        for (int off = 1; off < CW; off <<= 1) {
            float ap = __shfl_up(aL, off);
            float bp = __shfl_up(bL, off);
            if (lane >= off) { bL = aL * bp + bL; aL = aL * ap; }
        }
        float hin = __shfl_up(bL, 1);
        if (lane == 0) hin = 0.f;
        if constexpr (SPL == 4) {
            float4 B4 = *reinterpret_cast<const float4*>(bc + (size_t)(R_ + n) * L + base);
            float4 C4 = *reinterpret_cast<const float4*>(bc + (size_t)(R_ + N_ + n) * L + base);
            float h = hin;
            h = expf(dl[0] * An) * h + du[0] * B4.x; y[0] += h * C4.x;
            h = expf(dl[1] * An) * h + du[1] * B4.y; y[1] += h * C4.y;
            h = expf(dl[2] * An) * h + du[2] * B4.z; y[2] += h * C4.z;
            h = expf(dl[3] * An) * h + du[3] * B4.w; y[3] += h * C4.w;
        } else {
            float h = expf(dl[0] * An) * hin + du[0] * bc[(size_t)(R_ + n) * L + base];
            y[0] += h * bc[(size_t)(R_ + N_ + n) * L + base];
        }
    }

    if (lane < CW) {
#pragma unroll
        for (int i = 0; i < SPL; i++) {
            int src = dir_src(k, base + i, H, W, L);
            yb[(size_t)src * DI_] = y[i] + Dv * uu[i];
        }
    }
}

// --------------------------- merge 4 direction partials --------------------
__global__ void k_merge4(const float* __restrict__ part, float* __restrict__ ybuf,
                         int L) {
    int idx = blockIdx.x * 256 + threadIdx.x;    // (b,l,d)
    int total = B_ * L * DI_;
    if (idx >= total) return;
    int d = idx % DI_; int t = idx / DI_; int l = t % L; int bb = t / L;
    size_t s = ((size_t)bb * K_ * L + l) * DI_ + d;
    float v = part[s] + part[s + (size_t)L * DI_] + part[s + (size_t)2 * L * DI_]
            + part[s + (size_t)3 * L * DI_];
    ybuf[idx] = v;
}

// --------------------------- LN(y) * silu(z) -> t (B*L, DI) ----------------
__global__ void k_ln_silu(const float* __restrict__ y, const float* __restrict__ xz,
                          const float* __restrict__ onw, const float* __restrict__ onb,
                          float* __restrict__ tout) {
    int row = blockIdx.x;            // b*L + l
    __shared__ float sd[256];
    __shared__ float srow[DI_];
    const float* yp = y + (size_t)row * DI_;
    float sum = 0.f;
    for (int d = threadIdx.x; d < DI_; d += 256) { float v = yp[d]; srow[d] = v; sum += v; }
    sum = blockReduceSum(sum, sd);
    float mu = sum / DI_;
    float vs = 0.f;
    for (int d = threadIdx.x; d < DI_; d += 256) { float dv = srow[d] - mu; vs += dv * dv; }
    vs = blockReduceSum(vs, sd);
    float rstd = rsqrtf(vs / DI_ + 1e-5f);
    const float* zp = xz + (size_t)row * 2 * DI_ + DI_;
    float* tp = tout + (size_t)row * DI_;
    for (int d = threadIdx.x; d < DI_; d += 256) {
        float zn = zp[d];
        tp[d] = ((srow[d] - mu) * rstd * onw[d] + onb[d]) * siluf(zn);
    }
}

// --------------------------- downsample: dw conv s2 + BN + GELU ------------
__global__ void k_dwconv_s2_bn_gelu(const float* __restrict__ x, const float* __restrict__ dw,
                                    const float* __restrict__ bns, const float* __restrict__ bnb,
                                    float* __restrict__ out, int Hi, int Wi) {
    int Ho = Hi / 2, Wo = Wi / 2;
    int idx = blockIdx.x * 256 + threadIdx.x;            // (b,c,ho,wo)
    int total = B_ * C_ * Ho * Wo;
    if (idx >= total) return;
    int wo = idx % Wo; int t = idx / Wo; int ho = t % Ho; t /= Ho; int c = t % C_; int bb = t / C_;
    float acc = 0.f;
    const float* xp = x + ((size_t)bb * C_ + c) * Hi * Wi;
    const float* wp = dw + c * 9;
#pragma unroll
    for (int dy = 0; dy < 3; dy++) {
        int ih = ho * 2 + dy - 1;
        if ((unsigned)ih >= (unsigned)Hi) continue;
#pragma unroll
        for (int dx = 0; dx < 3; dx++) {
            int iw = wo * 2 + dx - 1;
            if ((unsigned)iw >= (unsigned)Wi) continue;
            acc += xp[ih * Wi + iw] * wp[dy * 3 + dx];
        }
    }
    acc = acc * (bns[c] * BNS_) + bnb[c];
    out[idx] = geluf(acc);
}

// --------------------------- pointwise 1x1 conv + BN + GELU ----------------
__global__ void k_pwconv_bn_gelu(const float* __restrict__ x, const float* __restrict__ pw,
                                 const float* __restrict__ bns, const float* __restrict__ bnb,
                                 float* __restrict__ out, int L) {
    int idx = blockIdx.x * 256 + threadIdx.x;            // (b,co,l)
    int total = B_ * C_ * L;
    if (idx >= total) return;
    int l = idx % L; int t = idx / L; int co = t % C_; int bb = t / C_;
    const float* xp = x + (size_t)bb * C_ * L + l;
    const float* wp = pw + (size_t)co * C_;
    float acc = 0.f;
    for (int ci = 0; ci < C_; ci++) acc += xp[(size_t)ci * L] * wp[ci];
    acc = acc * (bns[co] * BNS_) + bnb[co];
    out[idx] = geluf(acc);
}

// --------------------------- 3x3 conv, split-C partial (r11 body) ----------
__global__ void k_conv3x3_part(const float* __restrict__ x, const float* __restrict__ wgt,
                               float* __restrict__ partial, int H, int W) {
    const int COB = 4, CH = 4, SPLIT = 4;
    const int CSEG = C_ / SPLIT;         // 128
    int L = H * W;                       // == blockDim.x
    int t = threadIdx.x;
    int h = t / W, w = t % W;
    int blk = blockIdx.x;
    int s = blk % SPLIT; int t2 = blk / SPLIT;
    int ng = C_ / COB;
    int cg = t2 % ng; int bb = t2 / ng;
    int co0 = cg * COB;
    __shared__ float sp[2][CH * 256];
    float acc[COB];
#pragma unroll
    for (int j = 0; j < COB; j++) acc[j] = 0.f;
    const float* xb = x + (size_t)bb * C_ * L;
    int cbeg = s * CSEG;
    float4 pre = *reinterpret_cast<const float4*>(xb + (size_t)cbeg * L + 4 * t);
    int p = 0;
    for (int c0 = cbeg; c0 < cbeg + CSEG; c0 += CH) {
        *reinterpret_cast<float4*>(&sp[p][4 * t]) = pre;
        __syncthreads();
        if (c0 + CH < cbeg + CSEG)
            pre = *reinterpret_cast<const float4*>(xb + (size_t)(c0 + CH) * L + 4 * t);
#pragma unroll 1
        for (int ci = 0; ci < CH; ci++) {
            const float* pl = &sp[p][ci * L];
            float v[9];
#pragma unroll
            for (int dy = 0; dy < 3; dy++) {
                int hh = h + dy - 1;
                bool hok = (unsigned)hh < (unsigned)H;
#pragma unroll
                for (int dx = 0; dx < 3; dx++) {
                    int ww = w + dx - 1;
                    bool ok = hok && ((unsigned)ww < (unsigned)W);
                    v[dy * 3 + dx] = ok ? pl[hh * W + ww] : 0.f;
                }
            }
            const float* wr = wgt + ((size_t)co0 * C_ + c0 + ci) * 9;
#pragma unroll
            for (int j = 0; j < COB; j++) {
                const float* wj = wr + (size_t)j * C_ * 9;
                float a = acc[j];
                a += v[0] * wj[0] + v[1] * wj[1] + v[2] * wj[2];
                a += v[3] * wj[3] + v[4] * wj[4] + v[5] * wj[5];
                a += v[6] * wj[6] + v[7] * wj[7] + v[8] * wj[8];
                acc[j] = a;
            }
        }
        p ^= 1;
    }
    size_t base = (size_t)s * B_ * C_ * L;
#pragma unroll
    for (int j = 0; j < COB; j++)
        partial[base + ((size_t)bb * C_ + co0 + j) * L + t] = acc[j];
}

// --------------------------- conv finish: sum 4 partials + epilogue --------
template <int MODE>
__global__ void k_conv_fin(const float* __restrict__ part4, const float* __restrict__ bns,
                           const float* __restrict__ bnb, const float* __restrict__ res,
                           float* __restrict__ out, int L) {
    int idx = blockIdx.x * 256 + threadIdx.x;    // (b,c,l)
    int total = B_ * C_ * L;
    if (idx >= total) return;
    int c = (idx / L) % C_;
    size_t T = (size_t)total;
    float a = part4[idx] + part4[idx + T] + part4[idx + 2 * T] + part4[idx + 3 * T];
    a = a * (bns[c] * BNS_) + bnb[c];
    if (MODE == 0) out[idx] = geluf(a);
    else if (MODE == 1) out[idx] = geluf(a + res[idx]);
    else out[idx] = geluf(a) + res[idx];
}

// --------------------------- bilinear up + skip add ------------------------
__global__ void k_up_add(const float* __restrict__ low, const float* __restrict__ skip,
                         float* __restrict__ out, int Hi, int Wi, int Ho, int Wo) {
    int idx = blockIdx.x * 256 + threadIdx.x;            // (b,c,ho,wo)
    int total = B_ * C_ * Ho * Wo;
    if (idx >= total) return;
    int wo = idx % Wo; int t = idx / Wo; int ho = t % Ho; t /= Ho; int c = t % C_; int bb = t / C_;
    float fy = (float)ho * (float)(Hi - 1) / (float)(Ho - 1);
    float fx = (float)wo * (float)(Wi - 1) / (float)(Wo - 1);
    int y0 = (int)floorf(fy); int y1 = min(y0 + 1, Hi - 1); float wy = fy - (float)y0;
    int x0 = (int)floorf(fx); int x1 = min(x0 + 1, Wi - 1); float wx = fx - (float)x0;
    const float* lp = low + ((size_t)bb * C_ + c) * Hi * Wi;
    float g0 = lp[y0 * Wi + x0] * (1.f - wy) + lp[y1 * Wi + x0] * wy;
    float g1 = lp[y0 * Wi + x1] * (1.f - wy) + lp[y1 * Wi + x1] * wy;
    out[idx] = skip[idx] + g0 * (1.f - wx) + g1 * wx;
}

// --------------------------- BN + GELU elementwise -------------------------
__global__ void k_bn_gelu(const float* __restrict__ x, const float* __restrict__ s,
                          const float* __restrict__ b, float* __restrict__ out, int L) {
    int idx = blockIdx.x * 256 + threadIdx.x;            // (b,c,l)
    int total = B_ * C_ * L;
    if (idx >= total) return;
    int t = idx / L; int c = t % C_;
    out[idx] = geluf(x[idx] * (s[c] * BNS_) + b[c]);
}

// --------------------------- diagnostic fill (f32) -------------------------
__global__ void k_fill_out(float* o, int n, float v) {
    int i = blockIdx.x * 256 + threadIdx.x;
    if (i < n) o[i] = v;
}

// ===========================================================================
struct VssW {
    const float *lnw, *lnb, *inproj, *convw, *convb, *xproj, *dtw, *dtb, *Alog, *D, *onw, *onb, *outproj;
};

static void run_vss(const float* xc_in, float* xc_out, const VssW& p, int H, int W,
                    float* xln, float* xz, float* xm, float* xmT, float* xdbl,
                    float* part, float* ybuf, float* tbuf, hipStream_t stream) {
    int L = H * W, M = B_ * L;
    k_ln_nchw<<<M, 256, 0, stream>>>(xc_in, p.lnw, p.lnb, xln, L, 1e-6f);
    {
        dim3 g(2 * DI_ / 64, M / 64);
        k_gemm_nt<0><<<g, 256, 0, stream>>>(xln, p.inproj, xz, M, 2 * DI_, C_, nullptr, L);
    }
    {
        int tot = B_ * L * DI_;
        k_dwconv_silu<<<(tot + 255) / 256, 256, 0, stream>>>(xz, p.convw, p.convb, xm, xmT, H, W);
    }
    k_xdbl<<<B_ * K_ * L, 64, 0, stream>>>(xm, p.xproj, xdbl, H, W);
    {
        int g = B_ * K_ * (DI_ / 4);
        if (L == 256)
            k_scan_wave<256><<<g, 256, 0, stream>>>(xmT, xdbl, p.dtw, p.dtb, p.Alog, p.D, part, H, W);
        else if (L == 64)
            k_scan_wave<64><<<g, 256, 0, stream>>>(xmT, xdbl, p.dtw, p.dtb, p.Alog, p.D, part, H, W);
        else
            k_scan_wave<16><<<g, 256, 0, stream>>>(xmT, xdbl, p.dtw, p.dtb, p.Alog, p.D, part, H, W);
    }
    {
        int tot = B_ * L * DI_;
        k_merge4<<<(tot + 255) / 256, 256, 0, stream>>>(part, ybuf, L);
    }
    k_ln_silu<<<M, 256, 0, stream>>>(ybuf, xz, p.onw, p.onb, tbuf);
    {
        dim3 g(C_ / 64, M / 64);
        k_gemm_nt<1><<<g, 256, 0, stream>>>(tbuf, p.outproj, xc_out, M, C_, DI_, xc_in, L);
    }
}

extern "C" void kernel_launch(void* const* d_in, const int* in_sizes, int n_in,
                              void* d_out, int out_size, void* d_ws, size_t ws_size,
                              hipStream_t stream) {
    constexpr size_t NEED_FLOATS = 12124160;
    constexpr size_t NEED_BYTES  = NEED_FLOATS * 4;   // 48,496,640
    if (ws_size < NEED_BYTES) {
        k_fill_out<<<(out_size + 255) / 256, 256, 0, stream>>>((float*)d_out, out_size, 0.0f);
        return;
    }

    const float* x        = (const float*)d_in[0];
    const float* lnw      = (const float*)d_in[1];
    const float* lnb      = (const float*)d_in[2];
    const float* inproj   = (const float*)d_in[3];
    const float* convw    = (const float*)d_in[4];
    const float* convb    = (const float*)d_in[5];
    const float* xprojp   = (const float*)d_in[6];
    const float* dtwp     = (const float*)d_in[7];
    const float* dtbp     = (const float*)d_in[8];
    const float* Alogp    = (const float*)d_in[9];
    const float* Dpp      = (const float*)d_in[10];
    const float* onwp     = (const float*)d_in[11];
    const float* onbp     = (const float*)d_in[12];
    const float* outprojp = (const float*)d_in[13];
    const float* ds_dw    = (const float*)d_in[14];
    const float* ds_bn1s  = (const float*)d_in[15];
    const float* ds_bn1b  = (const float*)d_in[16];
    const float* ds_pw    = (const float*)d_in[17];
    const float* ds_bn2s  = (const float*)d_in[18];
    const float* ds_bn2b  = (const float*)d_in[19];
    const float* fus_c1   = (const float*)d_in[20];
    const float* fus_bn1s = (const float*)d_in[21];
    const float* fus_bn1b = (const float*)d_in[22];
    const float* fus_c2   = (const float*)d_in[23];
    const float* fus_bn2s = (const float*)d_in[24];
    const float* fus_bn2b = (const float*)d_in[25];
    const float* op_bn0s  = (const float*)d_in[26];
    const float* op_bn0b  = (const float*)d_in[27];
    const float* op_conv  = (const float*)d_in[28];
    const float* op_bn1s  = (const float*)d_in[29];
    const float* op_bn1b  = (const float*)d_in[30];

    float* ws = (float*)d_ws;
    float* xln   = ws;                    // 524288
    float* xz    = ws + 524288;           // 2097152
    float* xm    = ws + 2621440;          // 1048576
    float* xdbl  = ws + 3670016;          // 262144
    float* ybuf  = ws + 3932160;          // 1048576
    float* part  = ws + 4980736;          // 4194304
    float* tbuf  = part;                  // alias: part dead before ln_silu
    float* t_a   = ws + 9175040;          // 524288
    float* xr    = ws + 9699328;          // 524288
    float* p1    = ws + 10223616;         // 131072
    float* p2    = ws + 10354688;         // 32768
    float* proc0 = ws + 10387456;         // 524288
    float* proc1 = ws + 10911744;         // 131072
    float* proc2 = ws + 11042816;         // 32768
    float* xmT   = ws + 11075584;         // 1048576 (transposed xm)
    float* p1pre = xz;                    // 131072
    float* p2pre = xz + 131072;           // 32768
    float* up1t  = xln;                   // 131072
    float* rbh1  = xln + 131072;          // 131072
    float* fus1  = xln + 262144;          // 131072
    float* up0t  = xm;                    // 524288
    float* rbh0  = part;                  // 524288
    float* fus0  = part + 524288;         // 524288
    float* hbuf  = part + 1048576;        // 524288
    float* cpart = part + 1572864;        // 2097152 (4 conv partials)

    VssW vp[5];
    for (int i = 0; i < 5; i++) {
        vp[i].lnw     = lnw + (size_t)i * C_;
        vp[i].lnb     = lnb + (size_t)i * C_;
        vp[i].inproj  = inproj + (size_t)i * 2 * DI_ * C_;
        vp[i].convw   = convw + (size_t)i * DI_ * 9;
        vp[i].convb   = convb + (size_t)i * DI_;
        vp[i].xproj   = xprojp + (size_t)i * K_ * 64 * DI_;
        vp[i].dtw     = dtwp + (size_t)i * K_ * DI_ * R_;
        vp[i].dtb     = dtbp + (size_t)i * K_ * DI_;
        vp[i].Alog    = Alogp + (size_t)i * K_ * DI_ * N_;
        vp[i].D       = Dpp + (size_t)i * K_ * DI_;
        vp[i].onw     = onwp + (size_t)i * DI_;
        vp[i].onb     = onbp + (size_t)i * DI_;
        vp[i].outproj = outprojp + (size_t)i * C_ * DI_;
    }

    // ---- stem: two VSS at 16x16 ----
    run_vss(x,   t_a, vp[0], 16, 16, xln, xz, xm, xmT, xdbl, part, ybuf, tbuf, stream);
    run_vss(t_a, xr,  vp[1], 16, 16, xln, xz, xm, xmT, xdbl, part, ybuf, tbuf, stream);

    // ---- down 0: 16 -> 8 ----
    k_dwconv_s2_bn_gelu<<<(B_ * C_ * 64 + 255) / 256, 256, 0, stream>>>(
        xr, ds_dw, ds_bn1s, ds_bn1b, p1pre, 16, 16);
    k_pwconv_bn_gelu<<<(B_ * C_ * 64 + 255) / 256, 256, 0, stream>>>(
        p1pre, ds_pw, ds_bn2s, ds_bn2b, p1, 64);
    // ---- down 1: 8 -> 4 ----
    k_dwconv_s2_bn_gelu<<<(B_ * C_ * 16 + 255) / 256, 256, 0, stream>>>(
        p1, ds_dw + (size_t)C_ * 9, ds_bn1s + C_, ds_bn1b + C_, p2pre, 8, 8);
    k_pwconv_bn_gelu<<<(B_ * C_ * 16 + 255) / 256, 256, 0, stream>>>(
        p2pre, ds_pw + (size_t)C_ * C_, ds_bn2s + C_, ds_bn2b + C_, p2, 16);

    // ---- per-scale VSS ----
    run_vss(xr, proc0, vp[2], 16, 16, xln, xz, xm, xmT, xdbl, part, ybuf, tbuf, stream);
    run_vss(p1, proc1, vp[3],  8,  8, xln, xz, xm, xmT, xdbl, part, ybuf, tbuf, stream);
    run_vss(p2, proc2, vp[4],  4,  4, xln, xz, xm, xmT, xdbl, part, ybuf, tbuf, stream);

    // ---- fuse i=1: up(proc2: 4->8) + proc1, resblk j=0 ----
    k_up_add<<<(B_ * C_ * 64 + 255) / 256, 256, 0, stream>>>(proc2, proc1, up1t, 4, 4, 8, 8);
    {
        dim3 gp(B_ * (C_ / 4) * 4);
        int tot = B_ * C_ * 64;
        k_conv3x3_part<<<gp, 64, 0, stream>>>(up1t, fus_c1, cpart, 8, 8);
        k_conv_fin<0><<<(tot + 255) / 256, 256, 0, stream>>>(cpart, fus_bn1s, fus_bn1b,
                                                             nullptr, rbh1, 64);
        k_conv3x3_part<<<gp, 64, 0, stream>>>(rbh1, fus_c2, cpart, 8, 8);
        k_conv_fin<1><<<(tot + 255) / 256, 256, 0, stream>>>(cpart, fus_bn2s, fus_bn2b,
                                                             up1t, fus1, 64);
    }
    // ---- fuse i=0: up(fus1: 8->16) + proc0, resblk j=1 ----
    k_up_add<<<(B_ * C_ * 256 + 255) / 256, 256, 0, stream>>>(fus1, proc0, up0t, 8, 8, 16, 16);
    {
        dim3 gp(B_ * (C_ / 4) * 4);
        int tot = B_ * C_ * 256;
        k_conv3x3_part<<<gp, 256, 0, stream>>>(up0t, fus_c1 + (size_t)C_ * C_ * 9, cpart, 16, 16);
        k_conv_fin<0><<<(tot + 255) / 256, 256, 0, stream>>>(cpart, fus_bn1s + C_, fus_bn1b + C_,
                                                             nullptr, rbh0, 256);
        k_conv3x3_part<<<gp, 256, 0, stream>>>(rbh0, fus_c2 + (size_t)C_ * C_ * 9, cpart, 16, 16);
        k_conv_fin<1><<<(tot + 255) / 256, 256, 0, stream>>>(cpart, fus_bn2s + C_, fus_bn2b + C_,
                                                             up0t, fus0, 256);
    }

    // ---- output head ----
    k_bn_gelu<<<(B_ * C_ * 256 + 255) / 256, 256, 0, stream>>>(fus0, op_bn0s, op_bn0b, hbuf, 256);
    {
        dim3 gp(B_ * (C_ / 4) * 4);
        int tot = B_ * C_ * 256;
        k_conv3x3_part<<<gp, 256, 0, stream>>>(hbuf, op_conv, cpart, 16, 16);
        k_conv_fin<2><<<(tot + 255) / 256, 256, 0, stream>>>(cpart, op_bn1s, op_bn1b,
                                                             x, (float*)d_out, 256);
    }
    (void)in_sizes; (void)n_in; (void)out_size;
}

// Round 19
// 1916.846 us; speedup vs baseline: 1.3197x; 1.0336x over previous
//
#include <hip/hip_runtime.h>
#include <hip/hip_bf16.h>
#include <math.h>

// ---------------------------------------------------------------------------
// HMABottleneck: B=4, C=512, H=W=16, DI=1024, K=4 dirs, N=16 states, R=32
// Round 19: conv SPLIT 4 -> 8 (same lean body, VGPR 16; chain halves,
// 4096 blocks = 16/CU). conv_fin sums 8 partials. cpart extends in place
// (region through xmT is dead during fusion convs; liveness audited).
// Rest identical to round 18 (1.98 ms).
// ---------------------------------------------------------------------------

constexpr int B_  = 4;
constexpr int C_  = 512;
constexpr int DI_ = 1024;
constexpr int K_  = 4;
constexpr int N_  = 16;
constexpr int R_  = 32;
constexpr int CSPLIT_ = 8;                    // conv split-C factor
constexpr float BNS_ = 0.9999950000374997f;   // 1/sqrt(1+1e-5)

__device__ inline float geluf(float x) {
    return 0.5f * x * (1.0f + erff(x * 0.70710678118654752f));
}
__device__ inline float siluf(float x) {
    return x / (1.0f + expf(-x));
}
__device__ inline float softplusf(float x) {
    return fmaxf(x, 0.0f) + log1pf(expf(-fabsf(x)));
}

__device__ inline float blockReduceSum(float v, float* sd) {
    int tid = threadIdx.x;
    sd[tid] = v; __syncthreads();
    for (int s = blockDim.x / 2; s > 0; s >>= 1) {
        if (tid < s) sd[tid] += sd[tid + s];
        __syncthreads();
    }
    float r = sd[0]; __syncthreads();
    return r;
}

// --------------------------- LN over channels (NCHW -> (B*L, C)) -----------
__global__ void k_ln_nchw(const float* __restrict__ x, const float* __restrict__ w,
                          const float* __restrict__ b, float* __restrict__ out,
                          int L, float eps) {
    int row = blockIdx.x;            // b*L + l
    int bb = row / L, l = row % L;
    __shared__ float sd[256];
    __shared__ float srow[C_];
    const float* xp = x + (size_t)bb * C_ * L + l;
    float sum = 0.f;
    for (int c = threadIdx.x; c < C_; c += 256) { float v = xp[(size_t)c * L]; srow[c] = v; sum += v; }
    sum = blockReduceSum(sum, sd);
    float mu = sum / C_;
    float vs = 0.f;
    for (int c = threadIdx.x; c < C_; c += 256) { float d = srow[c] - mu; vs += d * d; }
    vs = blockReduceSum(vs, sd);
    float rstd = rsqrtf(vs / C_ + eps);
    float* op = out + (size_t)row * C_;
    for (int c = threadIdx.x; c < C_; c += 256) op[c] = (srow[c] - mu) * rstd * w[c] + b[c];
}

// --------------------------- tiled f32 GEMM: out = A (M,K) * Bw(N,K)^T -----
template <int EPI>
__global__ void k_gemm_nt(const float* __restrict__ A, const float* __restrict__ Bw,
                          float* __restrict__ Cout, int M, int Nn, int Kk,
                          const float* __restrict__ Res, int L) {
    const int BK = 16;
    __shared__ float As[BK][65];
    __shared__ float Bs[BK][65];
    int m0 = blockIdx.y * 64, n0 = blockIdx.x * 64;
    int tid = threadIdx.x;
    int tx = tid % 16, ty = tid / 16;
    float acc[4][4] = {};
    for (int k0 = 0; k0 < Kk; k0 += BK) {
        int mm = tid >> 2;
        int kk = (tid & 3) * 4;
        float4 va = *reinterpret_cast<const float4*>(A + (size_t)(m0 + mm) * Kk + k0 + kk);
        As[kk + 0][mm] = va.x; As[kk + 1][mm] = va.y; As[kk + 2][mm] = va.z; As[kk + 3][mm] = va.w;
        float4 vb = *reinterpret_cast<const float4*>(Bw + (size_t)(n0 + mm) * Kk + k0 + kk);
        Bs[kk + 0][mm] = vb.x; Bs[kk + 1][mm] = vb.y; Bs[kk + 2][mm] = vb.z; Bs[kk + 3][mm] = vb.w;
        __syncthreads();
#pragma unroll
        for (int k = 0; k < BK; ++k) {
            float a[4], b2[4];
#pragma unroll
            for (int i = 0; i < 4; i++) a[i] = As[k][ty + 16 * i];
#pragma unroll
            for (int j = 0; j < 4; j++) b2[j] = Bs[k][tx + 16 * j];
#pragma unroll
            for (int i = 0; i < 4; i++)
#pragma unroll
                for (int j = 0; j < 4; j++) acc[i][j] += a[i] * b2[j];
        }
        __syncthreads();
    }
#pragma unroll
    for (int i = 0; i < 4; i++) {
        int m = m0 + ty + 16 * i;
#pragma unroll
        for (int j = 0; j < 4; j++) {
            int n = n0 + tx + 16 * j;
            if (EPI == 0) {
                Cout[(size_t)m * Nn + n] = acc[i][j];
            } else {
                int bb = m / L, l = m % L;
                size_t o = ((size_t)bb * C_ + n) * L + l;
                Cout[o] = Res[o] + acc[i][j];
            }
        }
    }
}

// --------------------------- depthwise 3x3 (pad1) + bias + SiLU ------------
// writes xm (b,l,d) AND transposed xmT (b,d,l) for the wave-scan u-gather
__global__ void k_dwconv_silu(const float* __restrict__ xz, const float* __restrict__ cw,
                              const float* __restrict__ cb, float* __restrict__ xm,
                              float* __restrict__ xmT, int H, int W) {
    int L = H * W;
    int idx = blockIdx.x * 256 + threadIdx.x;            // (b, l, d) d fastest
    int total = B_ * L * DI_;
    if (idx >= total) return;
    int d = idx % DI_; int t = idx / DI_; int l = t % L; int bb = t / L;
    int h = l / W, w = l % W;
    float acc = cb[d];
    const float* wp = cw + d * 9;
#pragma unroll
    for (int dy = 0; dy < 3; dy++) {
        int hh = h + dy - 1;
        if ((unsigned)hh >= (unsigned)H) continue;
#pragma unroll
        for (int dx = 0; dx < 3; dx++) {
            int ww = w + dx - 1;
            if ((unsigned)ww >= (unsigned)W) continue;
            acc += xz[((size_t)bb * L + hh * W + ww) * (2 * DI_) + d] * wp[dy * 3 + dx];
        }
    }
    float v = siluf(acc);
    xm[idx] = v;
    xmT[((size_t)bb * DI_ + d) * L + l] = v;
}

// map (k,l) -> source flat index in row-major (h*W+w) order
__device__ inline int dir_src(int k, int l, int H, int W, int L) {
    int ll = (k >= 2) ? (L - 1 - l) : l;
    return (k & 1) ? ((ll % H) * W + ll / H) : ll;
}

// --------------------------- x_dbl (LDS row staging, 64 thr/block) ---------
__global__ void k_xdbl(const float* __restrict__ xm, const float* __restrict__ xproj,
                       float* __restrict__ xdbl, int H, int W) {
    int L = H * W;
    int blk = blockIdx.x;            // (b,k,l)
    int l = blk % L; int t = blk / L; int k = t % K_; int bb = t / K_;
    int src = dir_src(k, l, H, W, L);
    __shared__ float row[DI_];
    const float* xp = xm + ((size_t)bb * L + src) * DI_;
    for (int d = threadIdx.x; d < DI_; d += 64) row[d] = xp[d];
    __syncthreads();
    const float* wp = xproj + ((size_t)k * 64 + threadIdx.x) * DI_;
    float acc = 0.f;
    for (int d = 0; d < DI_; d++) acc += row[d] * wp[d];
    xdbl[((size_t)(bb * K_ + k) * 64 + threadIdx.x) * L + l] = acc;
}

// --------------------------- wave scan, SPL steps per lane (lean) ----------
// r18-proven: unroll-1 n-loop blocks cross-iteration float4 hoisting (the
// r16/r17 spill cause). One 64-lane wave per (b,k,d); lane owns SPL steps.
template <int LT>
__global__ void k_scan_wave(const float* __restrict__ xmT, const float* __restrict__ xdbl,
                            const float* __restrict__ dtw, const float* __restrict__ dtb,
                            const float* __restrict__ Alog, const float* __restrict__ Dp,
                            float* __restrict__ part, int H, int W) {
    constexpr int SPL = (LT == 256) ? 4 : 1;
    constexpr int CW  = (LT < 64) ? LT : 64;
    const int L = LT;
    int lane = threadIdx.x & 63;
    int wv = threadIdx.x >> 6;
    int blk = blockIdx.x;                // (bb, k, dq)
    const int ndq = DI_ / 4;
    int dq = blk % ndq; int t2 = blk / ndq; int k = t2 % K_; int bb = t2 / K_;
    int d = dq * 4 + wv;

    const float* wrow = dtw + ((size_t)k * DI_ + d) * R_;     // wave-uniform
    const float* al   = Alog + ((size_t)k * DI_ + d) * N_;    // wave-uniform
    float bias = dtb[k * DI_ + d];
    float Dv   = Dp[k * DI_ + d];

    const float* bc = xdbl + (size_t)(bb * K_ + k) * 64 * L;
    const float* ut = xmT + ((size_t)bb * DI_ + d) * L;
    float* yb = part + (size_t)(bb * K_ + k) * L * DI_ + d;

    int lj = lane < CW ? lane : CW - 1;      // lanes >= CW duplicate last step
    int base = lj * SPL;

    float dl[SPL], du[SPL], uu[SPL], y[SPL];
    {
        float accv[SPL];
#pragma unroll
        for (int i = 0; i < SPL; i++) accv[i] = bias;
#pragma unroll 8
        for (int r = 0; r < R_; r++) {
            float wr = wrow[r];
            if constexpr (SPL == 4) {
                float4 d4 = *reinterpret_cast<const float4*>(bc + (size_t)r * L + base);
                accv[0] += d4.x * wr; accv[1] += d4.y * wr;
                accv[2] += d4.z * wr; accv[3] += d4.w * wr;
            } else {
                accv[0] += bc[(size_t)r * L + base] * wr;
            }
        }
#pragma unroll
        for (int i = 0; i < SPL; i++) {
            int src = dir_src(k, base + i, H, W, L);
            dl[i] = softplusf(accv[i]);
            uu[i] = ut[src];
            du[i] = dl[i] * uu[i];
            y[i] = 0.f;
        }
    }

#pragma unroll 1
    for (int n = 0; n < N_; n++) {
        float An = -expf(al[n]);
        float aL, bL;
        if constexpr (SPL == 4) {
            float4 B4 = *reinterpret_cast<const float4*>(bc + (size_t)(R_ + n) * L + base);
            float a0 = expf(dl[0] * An);
            aL = a0; bL = du[0] * B4.x;
            float a1 = expf(dl[1] * An);
            bL = a1 * bL + du[1] * B4.y; aL = a1 * aL;
            float a2 = expf(dl[2] * An);
            bL = a2 * bL + du[2] * B4.z; aL = a2 * aL;
            float a3 = expf(dl[3] * An);
            bL = a3 * bL + du[3] * B4.w; aL = a3 * aL;
        } else {
            aL = expf(dl[0] * An);
            bL = du[0] * bc[(size_t)(R_ + n) * L + base];
        }
#pragma unroll
        for (int off = 1; off < CW; off <<= 1) {
            float ap = __shfl_up(aL, off);
            float bp = __shfl_up(bL, off);
            if (lane >= off) { bL = aL * bp + bL; aL = aL * ap; }
        }
        float hin = __shfl_up(bL, 1);
        if (lane == 0) hin = 0.f;
        if constexpr (SPL == 4) {
            float4 B4 = *reinterpret_cast<const float4*>(bc + (size_t)(R_ + n) * L + base);
            float4 C4 = *reinterpret_cast<const float4*>(bc + (size_t)(R_ + N_ + n) * L + base);
            float h = hin;
            h = expf(dl[0] * An) * h + du[0] * B4.x; y[0] += h * C4.x;
            h = expf(dl[1] * An) * h + du[1] * B4.y; y[1] += h * C4.y;
            h = expf(dl[2] * An) * h + du[2] * B4.z; y[2] += h * C4.z;
            h = expf(dl[3] * An) * h + du[3] * B4.w; y[3] += h * C4.w;
        } else {
            float h = expf(dl[0] * An) * hin + du[0] * bc[(size_t)(R_ + n) * L + base];
            y[0] += h * bc[(size_t)(R_ + N_ + n) * L + base];
        }
    }

    if (lane < CW) {
#pragma unroll
        for (int i = 0; i < SPL; i++) {
            int src = dir_src(k, base + i, H, W, L);
            yb[(size_t)src * DI_] = y[i] + Dv * uu[i];
        }
    }
}

// --------------------------- merge 4 direction partials --------------------
__global__ void k_merge4(const float* __restrict__ part, float* __restrict__ ybuf,
                         int L) {
    int idx = blockIdx.x * 256 + threadIdx.x;    // (b,l,d)
    int total = B_ * L * DI_;
    if (idx >= total) return;
    int d = idx % DI_; int t = idx / DI_; int l = t % L; int bb = t / L;
    size_t s = ((size_t)bb * K_ * L + l) * DI_ + d;
    float v = part[s] + part[s + (size_t)L * DI_] + part[s + (size_t)2 * L * DI_]
            + part[s + (size_t)3 * L * DI_];
    ybuf[idx] = v;
}

// --------------------------- LN(y) * silu(z) -> t (B*L, DI) ----------------
__global__ void k_ln_silu(const float* __restrict__ y, const float* __restrict__ xz,
                          const float* __restrict__ onw, const float* __restrict__ onb,
                          float* __restrict__ tout) {
    int row = blockIdx.x;            // b*L + l
    __shared__ float sd[256];
    __shared__ float srow[DI_];
    const float* yp = y + (size_t)row * DI_;
    float sum = 0.f;
    for (int d = threadIdx.x; d < DI_; d += 256) { float v = yp[d]; srow[d] = v; sum += v; }
    sum = blockReduceSum(sum, sd);
    float mu = sum / DI_;
    float vs = 0.f;
    for (int d = threadIdx.x; d < DI_; d += 256) { float dv = srow[d] - mu; vs += dv * dv; }
    vs = blockReduceSum(vs, sd);
    float rstd = rsqrtf(vs / DI_ + 1e-5f);
    const float* zp = xz + (size_t)row * 2 * DI_ + DI_;
    float* tp = tout + (size_t)row * DI_;
    for (int d = threadIdx.x; d < DI_; d += 256) {
        float zn = zp[d];
        tp[d] = ((srow[d] - mu) * rstd * onw[d] + onb[d]) * siluf(zn);
    }
}

// --------------------------- downsample: dw conv s2 + BN + GELU ------------
__global__ void k_dwconv_s2_bn_gelu(const float* __restrict__ x, const float* __restrict__ dw,
                                    const float* __restrict__ bns, const float* __restrict__ bnb,
                                    float* __restrict__ out, int Hi, int Wi) {
    int Ho = Hi / 2, Wo = Wi / 2;
    int idx = blockIdx.x * 256 + threadIdx.x;            // (b,c,ho,wo)
    int total = B_ * C_ * Ho * Wo;
    if (idx >= total) return;
    int wo = idx % Wo; int t = idx / Wo; int ho = t % Ho; t /= Ho; int c = t % C_; int bb = t / C_;
    float acc = 0.f;
    const float* xp = x + ((size_t)bb * C_ + c) * Hi * Wi;
    const float* wp = dw + c * 9;
#pragma unroll
    for (int dy = 0; dy < 3; dy++) {
        int ih = ho * 2 + dy - 1;
        if ((unsigned)ih >= (unsigned)Hi) continue;
#pragma unroll
        for (int dx = 0; dx < 3; dx++) {
            int iw = wo * 2 + dx - 1;
            if ((unsigned)iw >= (unsigned)Wi) continue;
            acc += xp[ih * Wi + iw] * wp[dy * 3 + dx];
        }
    }
    acc = acc * (bns[c] * BNS_) + bnb[c];
    out[idx] = geluf(acc);
}

// --------------------------- pointwise 1x1 conv + BN + GELU ----------------
__global__ void k_pwconv_bn_gelu(const float* __restrict__ x, const float* __restrict__ pw,
                                 const float* __restrict__ bns, const float* __restrict__ bnb,
                                 float* __restrict__ out, int L) {
    int idx = blockIdx.x * 256 + threadIdx.x;            // (b,co,l)
    int total = B_ * C_ * L;
    if (idx >= total) return;
    int l = idx % L; int t = idx / L; int co = t % C_; int bb = t / C_;
    const float* xp = x + (size_t)bb * C_ * L + l;
    const float* wp = pw + (size_t)co * C_;
    float acc = 0.f;
    for (int ci = 0; ci < C_; ci++) acc += xp[(size_t)ci * L] * wp[ci];
    acc = acc * (bns[co] * BNS_) + bnb[co];
    out[idx] = geluf(acc);
}

// --------------------------- 3x3 conv, split-C partial ---------------------
// SPLIT = CSPLIT_ (8). grid = B*(C/COB)*SPLIT blocks; block = L threads.
// Block (bb,cg,s) accumulates input channels [s*C/SPLIT, (s+1)*C/SPLIT) with
// the r11 lean chunk loop (CH=4 planes/barrier, float4 staging, 1-deep
// prefetch, unroll-1 ci loop; VGPR 16 proven). Writes partial[s].
__global__ void k_conv3x3_part(const float* __restrict__ x, const float* __restrict__ wgt,
                               float* __restrict__ partial, int H, int W) {
    const int COB = 4, CH = 4, SPLIT = CSPLIT_;
    const int CSEG = C_ / SPLIT;         // 64
    int L = H * W;                       // == blockDim.x
    int t = threadIdx.x;
    int h = t / W, w = t % W;
    int blk = blockIdx.x;
    int s = blk % SPLIT; int t2 = blk / SPLIT;
    int ng = C_ / COB;
    int cg = t2 % ng; int bb = t2 / ng;
    int co0 = cg * COB;
    __shared__ float sp[2][CH * 256];
    float acc[COB];
#pragma unroll
    for (int j = 0; j < COB; j++) acc[j] = 0.f;
    const float* xb = x + (size_t)bb * C_ * L;
    int cbeg = s * CSEG;
    float4 pre = *reinterpret_cast<const float4*>(xb + (size_t)cbeg * L + 4 * t);
    int p = 0;
    for (int c0 = cbeg; c0 < cbeg + CSEG; c0 += CH) {
        *reinterpret_cast<float4*>(&sp[p][4 * t]) = pre;
        __syncthreads();
        if (c0 + CH < cbeg + CSEG)
            pre = *reinterpret_cast<const float4*>(xb + (size_t)(c0 + CH) * L + 4 * t);
#pragma unroll 1
        for (int ci = 0; ci < CH; ci++) {
            const float* pl = &sp[p][ci * L];
            float v[9];
#pragma unroll
            for (int dy = 0; dy < 3; dy++) {
                int hh = h + dy - 1;
                bool hok = (unsigned)hh < (unsigned)H;
#pragma unroll
                for (int dx = 0; dx < 3; dx++) {
                    int ww = w + dx - 1;
                    bool ok = hok && ((unsigned)ww < (unsigned)W);
                    v[dy * 3 + dx] = ok ? pl[hh * W + ww] : 0.f;
                }
            }
            const float* wr = wgt + ((size_t)co0 * C_ + c0 + ci) * 9;
#pragma unroll
            for (int j = 0; j < COB; j++) {
                const float* wj = wr + (size_t)j * C_ * 9;
                float a = acc[j];
                a += v[0] * wj[0] + v[1] * wj[1] + v[2] * wj[2];
                a += v[3] * wj[3] + v[4] * wj[4] + v[5] * wj[5];
                a += v[6] * wj[6] + v[7] * wj[7] + v[8] * wj[8];
                acc[j] = a;
            }
        }
        p ^= 1;
    }
    size_t base = (size_t)s * B_ * C_ * L;
#pragma unroll
    for (int j = 0; j < COB; j++)
        partial[base + ((size_t)bb * C_ + co0 + j) * L + t] = acc[j];
}

// --------------------------- conv finish: sum CSPLIT_ partials + epilogue --
// MODE 0: out = gelu(bn(conv));  MODE 1: out = gelu(bn(conv)+res)
// MODE 2: out = gelu(bn(conv)) + res   (final head output, f32)
template <int MODE>
__global__ void k_conv_fin(const float* __restrict__ partN, const float* __restrict__ bns,
                           const float* __restrict__ bnb, const float* __restrict__ res,
                           float* __restrict__ out, int L) {
    int idx = blockIdx.x * 256 + threadIdx.x;    // (b,c,l)
    int total = B_ * C_ * L;
    if (idx >= total) return;
    int c = (idx / L) % C_;
    size_t T = (size_t)total;
    float a = 0.f;
#pragma unroll
    for (int s = 0; s < CSPLIT_; s++) a += partN[idx + (size_t)s * T];
    a = a * (bns[c] * BNS_) + bnb[c];
    if (MODE == 0) out[idx] = geluf(a);
    else if (MODE == 1) out[idx] = geluf(a + res[idx]);
    else out[idx] = geluf(a) + res[idx];
}

// --------------------------- bilinear up + skip add ------------------------
__global__ void k_up_add(const float* __restrict__ low, const float* __restrict__ skip,
                         float* __restrict__ out, int Hi, int Wi, int Ho, int Wo) {
    int idx = blockIdx.x * 256 + threadIdx.x;            // (b,c,ho,wo)
    int total = B_ * C_ * Ho * Wo;
    if (idx >= total) return;
    int wo = idx % Wo; int t = idx / Wo; int ho = t % Ho; t /= Ho; int c = t % C_; int bb = t / C_;
    float fy = (float)ho * (float)(Hi - 1) / (float)(Ho - 1);
    float fx = (float)wo * (float)(Wi - 1) / (float)(Wo - 1);
    int y0 = (int)floorf(fy); int y1 = min(y0 + 1, Hi - 1); float wy = fy - (float)y0;
    int x0 = (int)floorf(fx); int x1 = min(x0 + 1, Wi - 1); float wx = fx - (float)x0;
    const float* lp = low + ((size_t)bb * C_ + c) * Hi * Wi;
    float g0 = lp[y0 * Wi + x0] * (1.f - wy) + lp[y1 * Wi + x0] * wy;
    float g1 = lp[y0 * Wi + x1] * (1.f - wy) + lp[y1 * Wi + x1] * wy;
    out[idx] = skip[idx] + g0 * (1.f - wx) + g1 * wx;
}

// --------------------------- BN + GELU elementwise -------------------------
__global__ void k_bn_gelu(const float* __restrict__ x, const float* __restrict__ s,
                          const float* __restrict__ b, float* __restrict__ out, int L) {
    int idx = blockIdx.x * 256 + threadIdx.x;            // (b,c,l)
    int total = B_ * C_ * L;
    if (idx >= total) return;
    int t = idx / L; int c = t % C_;
    out[idx] = geluf(x[idx] * (s[c] * BNS_) + b[c]);
}

// --------------------------- diagnostic fill (f32) -------------------------
__global__ void k_fill_out(float* o, int n, float v) {
    int i = blockIdx.x * 256 + threadIdx.x;
    if (i < n) o[i] = v;
}

// ===========================================================================
struct VssW {
    const float *lnw, *lnb, *inproj, *convw, *convb, *xproj, *dtw, *dtb, *Alog, *D, *onw, *onb, *outproj;
};

static void run_vss(const float* xc_in, float* xc_out, const VssW& p, int H, int W,
                    float* xln, float* xz, float* xm, float* xmT, float* xdbl,
                    float* part, float* ybuf, float* tbuf, hipStream_t stream) {
    int L = H * W, M = B_ * L;
    k_ln_nchw<<<M, 256, 0, stream>>>(xc_in, p.lnw, p.lnb, xln, L, 1e-6f);
    {
        dim3 g(2 * DI_ / 64, M / 64);
        k_gemm_nt<0><<<g, 256, 0, stream>>>(xln, p.inproj, xz, M, 2 * DI_, C_, nullptr, L);
    }
    {
        int tot = B_ * L * DI_;
        k_dwconv_silu<<<(tot + 255) / 256, 256, 0, stream>>>(xz, p.convw, p.convb, xm, xmT, H, W);
    }
    k_xdbl<<<B_ * K_ * L, 64, 0, stream>>>(xm, p.xproj, xdbl, H, W);
    {
        int g = B_ * K_ * (DI_ / 4);
        if (L == 256)
            k_scan_wave<256><<<g, 256, 0, stream>>>(xmT, xdbl, p.dtw, p.dtb, p.Alog, p.D, part, H, W);
        else if (L == 64)
            k_scan_wave<64><<<g, 256, 0, stream>>>(xmT, xdbl, p.dtw, p.dtb, p.Alog, p.D, part, H, W);
        else
            k_scan_wave<16><<<g, 256, 0, stream>>>(xmT, xdbl, p.dtw, p.dtb, p.Alog, p.D, part, H, W);
    }
    {
        int tot = B_ * L * DI_;
        k_merge4<<<(tot + 255) / 256, 256, 0, stream>>>(part, ybuf, L);
    }
    k_ln_silu<<<M, 256, 0, stream>>>(ybuf, xz, p.onw, p.onb, tbuf);
    {
        dim3 g(C_ / 64, M / 64);
        k_gemm_nt<1><<<g, 256, 0, stream>>>(tbuf, p.outproj, xc_out, M, C_, DI_, xc_in, L);
    }
}

extern "C" void kernel_launch(void* const* d_in, const int* in_sizes, int n_in,
                              void* d_out, int out_size, void* d_ws, size_t ws_size,
                              hipStream_t stream) {
    constexpr size_t NEED_FLOATS = 12124160;
    constexpr size_t NEED_BYTES  = NEED_FLOATS * 4;   // 48,496,640
    if (ws_size < NEED_BYTES) {
        k_fill_out<<<(out_size + 255) / 256, 256, 0, stream>>>((float*)d_out, out_size, 0.0f);
        return;
    }

    const float* x        = (const float*)d_in[0];
    const float* lnw      = (const float*)d_in[1];
    const float* lnb      = (const float*)d_in[2];
    const float* inproj   = (const float*)d_in[3];
    const float* convw    = (const float*)d_in[4];
    const float* convb    = (const float*)d_in[5];
    const float* xprojp   = (const float*)d_in[6];
    const float* dtwp     = (const float*)d_in[7];
    const float* dtbp     = (const float*)d_in[8];
    const float* Alogp    = (const float*)d_in[9];
    const float* Dpp      = (const float*)d_in[10];
    const float* onwp     = (const float*)d_in[11];
    const float* onbp     = (const float*)d_in[12];
    const float* outprojp = (const float*)d_in[13];
    const float* ds_dw    = (const float*)d_in[14];
    const float* ds_bn1s  = (const float*)d_in[15];
    const float* ds_bn1b  = (const float*)d_in[16];
    const float* ds_pw    = (const float*)d_in[17];
    const float* ds_bn2s  = (const float*)d_in[18];
    const float* ds_bn2b  = (const float*)d_in[19];
    const float* fus_c1   = (const float*)d_in[20];
    const float* fus_bn1s = (const float*)d_in[21];
    const float* fus_bn1b = (const float*)d_in[22];
    const float* fus_c2   = (const float*)d_in[23];
    const float* fus_bn2s = (const float*)d_in[24];
    const float* fus_bn2b = (const float*)d_in[25];
    const float* op_bn0s  = (const float*)d_in[26];
    const float* op_bn0b  = (const float*)d_in[27];
    const float* op_conv  = (const float*)d_in[28];
    const float* op_bn1s  = (const float*)d_in[29];
    const float* op_bn1b  = (const float*)d_in[30];

    float* ws = (float*)d_ws;
    float* xln   = ws;                    // 524288
    float* xz    = ws + 524288;           // 2097152
    float* xm    = ws + 2621440;          // 1048576
    float* xdbl  = ws + 3670016;          // 262144
    float* ybuf  = ws + 3932160;          // 1048576
    float* part  = ws + 4980736;          // 4194304
    float* tbuf  = part;                  // alias: part dead before ln_silu
    float* t_a   = ws + 9175040;          // 524288
    float* xr    = ws + 9699328;          // 524288
    float* p1    = ws + 10223616;         // 131072
    float* p2    = ws + 10354688;         // 32768
    float* proc0 = ws + 10387456;         // 524288
    float* proc1 = ws + 10911744;         // 131072
    float* proc2 = ws + 11042816;         // 32768
    float* xmT   = ws + 11075584;         // 1048576 (transposed xm)
    float* p1pre = xz;                    // 131072
    float* p2pre = xz + 131072;           // 32768
    // fusion temps: rbh/fus/hbuf in part[0..1.5M)
    float* up1t  = xln;                   // 131072
    float* rbh1  = xln + 131072;          // 131072
    float* fus1  = xln + 262144;          // 131072
    float* up0t  = xm;                    // 524288
    float* rbh0  = part;                  // 524288
    float* fus0  = part + 524288;         // 524288
    float* hbuf  = part + 1048576;        // 524288
    // cpart: CSPLIT_ * B*C*L_max = 8 * 524288 = 4.19M floats starting at
    // part+1572864 (= ws+6553600), extending through t_a/xr/p1/p2/proc0-2
    // (ends ws+10747904 < xmT@11075584). All those buffers are DEAD during
    // every conv3x3_part/conv_fin call (liveness audited vs launch order:
    // 8x8 convs run after proc1/proc2 consumed; 16x16 convs after proc0
    // consumed; t_a/xr/p1/p2/xmT dead after the VSS phase).
    float* cpart = part + 1572864;

    VssW vp[5];
    for (int i = 0; i < 5; i++) {
        vp[i].lnw     = lnw + (size_t)i * C_;
        vp[i].lnb     = lnb + (size_t)i * C_;
        vp[i].inproj  = inproj + (size_t)i * 2 * DI_ * C_;
        vp[i].convw   = convw + (size_t)i * DI_ * 9;
        vp[i].convb   = convb + (size_t)i * DI_;
        vp[i].xproj   = xprojp + (size_t)i * K_ * 64 * DI_;
        vp[i].dtw     = dtwp + (size_t)i * K_ * DI_ * R_;
        vp[i].dtb     = dtbp + (size_t)i * K_ * DI_;
        vp[i].Alog    = Alogp + (size_t)i * K_ * DI_ * N_;
        vp[i].D       = Dpp + (size_t)i * K_ * DI_;
        vp[i].onw     = onwp + (size_t)i * DI_;
        vp[i].onb     = onbp + (size_t)i * DI_;
        vp[i].outproj = outprojp + (size_t)i * C_ * DI_;
    }

    // ---- stem: two VSS at 16x16 ----
    run_vss(x,   t_a, vp[0], 16, 16, xln, xz, xm, xmT, xdbl, part, ybuf, tbuf, stream);
    run_vss(t_a, xr,  vp[1], 16, 16, xln, xz, xm, xmT, xdbl, part, ybuf, tbuf, stream);

    // ---- down 0: 16 -> 8 ----
    k_dwconv_s2_bn_gelu<<<(B_ * C_ * 64 + 255) / 256, 256, 0, stream>>>(
        xr, ds_dw, ds_bn1s, ds_bn1b, p1pre, 16, 16);
    k_pwconv_bn_gelu<<<(B_ * C_ * 64 + 255) / 256, 256, 0, stream>>>(
        p1pre, ds_pw, ds_bn2s, ds_bn2b, p1, 64);
    // ---- down 1: 8 -> 4 ----
    k_dwconv_s2_bn_gelu<<<(B_ * C_ * 16 + 255) / 256, 256, 0, stream>>>(
        p1, ds_dw + (size_t)C_ * 9, ds_bn1s + C_, ds_bn1b + C_, p2pre, 8, 8);
    k_pwconv_bn_gelu<<<(B_ * C_ * 16 + 255) / 256, 256, 0, stream>>>(
        p2pre, ds_pw + (size_t)C_ * C_, ds_bn2s + C_, ds_bn2b + C_, p2, 16);

    // ---- per-scale VSS ----
    run_vss(xr, proc0, vp[2], 16, 16, xln, xz, xm, xmT, xdbl, part, ybuf, tbuf, stream);
    run_vss(p1, proc1, vp[3],  8,  8, xln, xz, xm, xmT, xdbl, part, ybuf, tbuf, stream);
    run_vss(p2, proc2, vp[4],  4,  4, xln, xz, xm, xmT, xdbl, part, ybuf, tbuf, stream);

    // ---- fuse i=1: up(proc2: 4->8) + proc1, resblk j=0 ----
    k_up_add<<<(B_ * C_ * 64 + 255) / 256, 256, 0, stream>>>(proc2, proc1, up1t, 4, 4, 8, 8);
    {
        dim3 gp(B_ * (C_ / 4) * CSPLIT_);
        int tot = B_ * C_ * 64;
        k_conv3x3_part<<<gp, 64, 0, stream>>>(up1t, fus_c1, cpart, 8, 8);
        k_conv_fin<0><<<(tot + 255) / 256, 256, 0, stream>>>(cpart, fus_bn1s, fus_bn1b,
                                                             nullptr, rbh1, 64);
        k_conv3x3_part<<<gp, 64, 0, stream>>>(rbh1, fus_c2, cpart, 8, 8);
        k_conv_fin<1><<<(tot + 255) / 256, 256, 0, stream>>>(cpart, fus_bn2s, fus_bn2b,
                                                             up1t, fus1, 64);
    }
    // ---- fuse i=0: up(fus1: 8->16) + proc0, resblk j=1 ----
    k_up_add<<<(B_ * C_ * 256 + 255) / 256, 256, 0, stream>>>(fus1, proc0, up0t, 8, 8, 16, 16);
    {
        dim3 gp(B_ * (C_ / 4) * CSPLIT_);
        int tot = B_ * C_ * 256;
        k_conv3x3_part<<<gp, 256, 0, stream>>>(up0t, fus_c1 + (size_t)C_ * C_ * 9, cpart, 16, 16);
        k_conv_fin<0><<<(tot + 255) / 256, 256, 0, stream>>>(cpart, fus_bn1s + C_, fus_bn1b + C_,
                                                             nullptr, rbh0, 256);
        k_conv3x3_part<<<gp, 256, 0, stream>>>(rbh0, fus_c2 + (size_t)C_ * C_ * 9, cpart, 16, 16);
        k_conv_fin<1><<<(tot + 255) / 256, 256, 0, stream>>>(cpart, fus_bn2s + C_, fus_bn2b + C_,
                                                             up0t, fus0, 256);
    }

    // ---- output head ----
    k_bn_gelu<<<(B_ * C_ * 256 + 255) / 256, 256, 0, stream>>>(fus0, op_bn0s, op_bn0b, hbuf, 256);
    {
        dim3 gp(B_ * (C_ / 4) * CSPLIT_);
        int tot = B_ * C_ * 256;
        k_conv3x3_part<<<gp, 256, 0, stream>>>(hbuf, op_conv, cpart, 16, 16);
        k_conv_fin<2><<<(tot + 255) / 256, 256, 0, stream>>>(cpart, op_bn1s, op_bn1b,
                                                             x, (float*)d_out, 256);
    }
    (void)in_sizes; (void)n_in; (void)out_size;
}